// Round 8
// baseline (195.284 us; speedup 1.0000x reference)
//
#include <hip/hip_runtime.h>

// Problem constants (fixed by reference)
#define B_    2
#define NH_   4
#define T_    8
#define H_    14
#define W_    14
#define HW_   196             // H*W
#define HD_   96
#define DIM_  384
#define N_    1568            // T*H*W
#define BH_   (B_*NH_)        // 8
#define BN_   (B_*N_)         // 3136
#define BHN_  (BH_*N_)        // 12544
#define CAUG_ 160             // 96 + 36 one-hot/bias + 28 pad

typedef unsigned short bf_t;
typedef unsigned int   u32;
typedef __attribute__((ext_vector_type(8))) short bf16x8;
typedef __attribute__((ext_vector_type(4))) float f32x4;

#define LOG2E 1.4426950408889634f
#define QSCALE_LOG2E 0.14724445f   /* 96^-0.5 * log2(e) */

static __device__ __forceinline__ float lo16(u32 v){ union{u32 i; float f;}x; x.i = v<<16;           return x.f; }
static __device__ __forceinline__ float hi16(u32 v){ union{u32 i; float f;}x; x.i = v & 0xffff0000u; return x.f; }
static __device__ __forceinline__ float b2f(bf_t v){ union{u32 i; float f;}x; x.i = ((u32)v)<<16;    return x.f; }
static __device__ __forceinline__ bf_t  f2b(float f){
  union{float f; u32 i;} x; x.f = f;
  return (bf_t)((x.i + 0x7fffu + ((x.i>>16)&1u)) >> 16);   // RNE
}
static __device__ __forceinline__ u32 pack2(float a, float b){
  return (u32)f2b(a) | ((u32)f2b(b) << 16);
}
// fragment-tile index for a row-major [R][384] matrix element (row, k)
static __device__ __forceinline__ size_t ftidx(int row, int k){
  return ((((size_t)(row>>4))*12 + (k>>5))*64 + ((k>>3)&3)*16 + (row&15))*8 + (k&7);
}

// ---------------------------------------------------------------------------
// K0: cast x / qkv_w / proj_w fp32 -> bf16 in FRAGMENT-TILED layout, plus
// conv-weight transpose [96][27]->[27][96] fp32 (last 31 blocks).
// ---------------------------------------------------------------------------
#define NA_ (BN_*DIM_)        // 1,204,224
#define NB_ (3*DIM_*DIM_)     //   442,368
#define NC_ (DIM_*DIM_)       //   147,456
#define CAST_BLOCKS ((NA_+NB_+NC_)/4/256)   // 1752 exactly

__global__ __launch_bounds__(256) void k_cast(
    const float* __restrict__ a, bf_t* __restrict__ ad,
    const float* __restrict__ b, bf_t* __restrict__ bd,
    const float* __restrict__ c, bf_t* __restrict__ cd,
    const float* __restrict__ wq, const float* __restrict__ wk,
    const float* __restrict__ wv, float* __restrict__ tq,
    float* __restrict__ tk, float* __restrict__ tv){
  if (blockIdx.x < CAST_BLOCKS){
    const int i = blockIdx.x*256 + threadIdx.x;     // float4 index
    const int i4 = i*4;
    float4 v; bf_t* dst; int row, k;
    if (i4 < NA_){
      v = ((const float4*)a)[i];
      dst = ad; row = i4/DIM_; k = i4%DIM_;
    } else if (i4 < NA_+NB_){
      const int f = i4 - NA_;
      v = ((const float4*)b)[i - NA_/4];
      dst = bd; row = f/DIM_; k = f%DIM_;
    } else {
      const int f = i4 - NA_ - NB_;
      v = ((const float4*)c)[i - (NA_+NB_)/4];
      dst = cd; row = f/DIM_; k = f%DIM_;
    }
    ushort4 o; o.x = f2b(v.x); o.y = f2b(v.y); o.z = f2b(v.z); o.w = f2b(v.w);
    *(ushort4*)(dst + ftidx(row, k)) = o;           // k%4==0 -> 8B aligned
  } else {
    const int idx = (blockIdx.x - CAST_BLOCKS)*256 + threadIdx.x;
    if (idx >= 3*HD_*27) return;
    const int t = idx / (HD_*27), rem = idx % (HD_*27);
    const int ch = rem / 27, j = rem % 27;
    const float* s = (t==0)? wq : (t==1)? wk : wv;
    float* d       = (t==0)? tq : (t==1)? tk : tv;
    d[j*HD_ + ch] = s[ch*27 + j];
  }
}

// ---------------------------------------------------------------------------
// K1: QKV GEMM via MFMA, fragment-tiled operands.
// ---------------------------------------------------------------------------
__global__ __launch_bounds__(256) void k_qkv(const bf_t* __restrict__ Xt,
    const bf_t* __restrict__ Wt,
    bf_t* __restrict__ q, bf_t* __restrict__ k, bf_t* __restrict__ v){
  const int wid = threadIdx.x >> 6, lane = threadIdx.x & 63;
  const int wr = wid & 1, wc = wid >> 1;
  const int nl = lane & 15, quad = lane >> 4;
  const int r0 = blockIdx.x*64 + wr*32;
  const int mt0 = r0 >> 4;
  const int nt0 = blockIdx.y*8 + wc*4;
  f32x4 acc[2][4];
  #pragma unroll
  for (int i = 0; i < 2; ++i)
    #pragma unroll
    for (int j = 0; j < 4; ++j) acc[i][j] = (f32x4){0.f,0.f,0.f,0.f};
  const bf_t* A0 = Xt + ((size_t)mt0*12*64 + lane)*8;
  const bf_t* B0 = Wt + ((size_t)nt0*12*64 + lane)*8;
  #pragma unroll 2
  for (int k0 = 0; k0 < 12; ++k0){
    const bf16x8 a0 = *(const bf16x8*)(A0 + k0*512);
    const bf16x8 a1 = *(const bf16x8*)(A0 + 12*512 + k0*512);
    bf16x8 bf[4];
    #pragma unroll
    for (int j = 0; j < 4; ++j) bf[j] = *(const bf16x8*)(B0 + (size_t)(j*12 + k0)*512);
    #pragma unroll
    for (int j = 0; j < 4; ++j){
      acc[0][j] = __builtin_amdgcn_mfma_f32_16x16x32_bf16(a0, bf[j], acc[0][j], 0, 0, 0);
      acc[1][j] = __builtin_amdgcn_mfma_f32_16x16x32_bf16(a1, bf[j], acc[1][j], 0, 0, 0);
    }
  }
  #pragma unroll
  for (int i = 0; i < 2; ++i){
    #pragma unroll
    for (int r = 0; r < 4; ++r){
      const int m  = r0 + i*16 + quad*4 + r;
      const int bb = m / N_, nn = m % N_;
      #pragma unroll
      for (int j = 0; j < 4; ++j){
        const int col = (nt0 + j)*16 + nl;
        const int s = col / DIM_, rem = col - s*DIM_;
        const int head = rem / HD_, hc = rem % HD_;
        bf_t* dst = (s==0) ? q : (s==1) ? k : v;
        dst[((size_t)(bb*NH_ + head)*N_ + nn)*HD_ + hc] = f2b(acc[i][j][r]);
      }
    }
  }
}

static __device__ __forceinline__ void ln_butterfly(
    float v0, float v1, float& mean, float& rstd){
  float s  = v0 + v1;
  float s2 = v0*v0 + v1*v1;
  #pragma unroll
  for (int off = 32; off > 0; off >>= 1){
    s  += __shfl_xor(s,  off);
    s2 += __shfl_xor(s2, off);
  }
  mean = s * (1.f/HD_);
  const float var = fmaxf(s2*(1.f/HD_) - mean*mean, 0.f);
  rstd = rsqrtf(var + 1e-6f);
}

// ---------------------------------------------------------------------------
// K2: LDS-slab pooled conv+LN, 16 tokens/block (4 waves x 4 tokens).
// Halo slab 162 rows (3t x 3h x 18w) x 96ch bf16 = 31.1 KB.
// R19 decode retained: bh = blockIdx.x & 7 (XCD-pinned; FETCH 22.2->3.9 MB
// verified). Compute structure = R16 (proven best at ~48 us).
// ---------------------------------------------------------------------------
union PoolSM {
  bf_t  slab[162][HD_];       // 31,104 B  (phase 1)
  float qtmp[4][4][HD_];      //  6,144 B  (phase 2, sec 0; per-wave)
  u32   vres[16][48];         //  3,072 B  (phase 2, sec 2)
};

__global__ __launch_bounds__(256) void k_pool_slab(
    const bf_t* __restrict__ qr_, const bf_t* __restrict__ kr_, const bf_t* __restrict__ vr_,
    const float* __restrict__ wtq, const float* __restrict__ wtk, const float* __restrict__ wtv,
    const float* __restrict__ gq, const float* __restrict__ bq,
    const float* __restrict__ gk, const float* __restrict__ bk,
    const float* __restrict__ gv, const float* __restrict__ bv,
    const float* __restrict__ rph, const float* __restrict__ rpw,
    const float* __restrict__ rpt,
    bf_t* __restrict__ qp, bf_t* __restrict__ Qaug,
    bf_t* __restrict__ Kt, bf_t* __restrict__ Vtt){
  __shared__ __align__(16) PoolSM sm;
  const int wid = threadIdx.x >> 6, lane = threadIdx.x & 63;
  const int bh   = blockIdx.x & 7;          // XCD-pinned (2352 = 8 x 294)
  const int rest = blockIdx.x >> 3;
  const int sec  = rest / 98;
  const int tok0 = (rest % 98)*16;
  const bf_t*  src = (sec==0)? qr_ : (sec==1)? kr_ : vr_;
  const float* wt  = (sec==0)? wtq : (sec==1)? wtk : wtv;
  const float* g   = (sec==0)? gq  : (sec==1)? gk  : gv;
  const float* be  = (sec==0)? bq  : (sec==1)? bk  : bv;
  const bf_t* base = src + (size_t)bh*N_*HD_;

  // per-lane channel pair; first weight trio + LN params overlap staging
  const int c0 = (lane < 48) ? 2*lane : 0;
  float2 wcur[3], wnxt[3];
  #pragma unroll
  for (int dw = 0; dw < 3; ++dw) wcur[dw] = *(const float2*)(wt + dw*HD_ + c0);
  const float gg0 = g[c0], gg1 = g[c0+1], be0 = be[c0], be1 = be[c0+1];

  // ---- staging: batched loads into regs, then LDS writes (vmcnt pipeline) --
  {
    uint4 stg[8];
    #pragma unroll
    for (int it = 0; it < 8; ++it){
      const int li = threadIdx.x + it*256;
      const int lc = (li < 162*12) ? li : (162*12 - 1);
      const int rw = lc / 12, ss = lc % 12;
      const int aa = rw/54, bb2 = (rw%54)/18, cc = rw%18;
      int nn = tok0 + (aa-1)*HW_ + (bb2-1)*W_ + (cc-1);
      nn = min(max(nn, 0), N_-1);
      stg[it] = *(const uint4*)(base + (size_t)nn*HD_ + ss*8);
    }
    #pragma unroll
    for (int it = 0; it < 8; ++it){
      const int li = threadIdx.x + it*256;
      if (li < 162*12){
        const int rw = li / 12, ss = li % 12;
        *(uint4*)&sm.slab[rw][ss*8] = stg[it];
      }
    }
  }
  __syncthreads();

  // token coordinates (wave-uniform) + 27-bit validity masks
  int tt[4], hh[4], ww[4];
  u32 mr[4];
  #pragma unroll
  for (int tk = 0; tk < 4; ++tk){
    const int n = tok0 + wid*4 + tk;
    tt[tk] = n / HW_;
    const int rm = n % HW_;
    hh[tk] = rm / W_; ww[tk] = rm % W_;
    const u32 wb = (ww[tk] > 0 ? 1u : 0u) | 2u | (ww[tk] < W_-1 ? 4u : 0u);
    const u32 h9 = (hh[tk] > 0 ? wb : 0u) | (wb << 3) | (hh[tk] < H_-1 ? (wb << 6) : 0u);
    mr[tk] = (tt[tk] > 0 ? h9 : 0u) | (h9 << 9) | (tt[tk] < T_-1 ? (h9 << 18) : 0u);
  }

  // ---- phase 1: conv, software-pipelined row reads ----
  float v0[4] = {0.f,0.f,0.f,0.f}, v1[4] = {0.f,0.f,0.f,0.f};
  u32 rr[6], rrn[6];
  #pragma unroll
  for (int s = 0; s < 6; ++s) rr[s] = *(const u32*)&sm.slab[wid*4 + s][c0];
  #pragma unroll 1
  for (int j9 = 0; j9 < 9; ++j9){
    if (j9 < 8){
      const int jn = j9 + 1;
      const int rbn = (jn/3)*54 + (jn%3)*18 + wid*4;
      #pragma unroll
      for (int s = 0; s < 6; ++s) rrn[s] = *(const u32*)&sm.slab[rbn + s][c0];
      #pragma unroll
      for (int dw = 0; dw < 3; ++dw)
        wnxt[dw] = *(const float2*)(wt + (jn*3 + dw)*HD_ + c0);
    }
    #pragma unroll
    for (int tk = 0; tk < 4; ++tk){
      #pragma unroll
      for (int dw = 0; dw < 3; ++dw){
        const u32 d = (mr[tk] & (1u << dw)) ? rr[tk+dw] : 0u;
        v0[tk] = fmaf(wcur[dw].x, lo16(d), v0[tk]);
        v1[tk] = fmaf(wcur[dw].y, hi16(d), v1[tk]);
      }
      mr[tk] >>= 3;
    }
    #pragma unroll
    for (int s = 0; s < 6; ++s) rr[s] = rrn[s];
    #pragma unroll
    for (int dw = 0; dw < 3; ++dw) wcur[dw] = wnxt[dw];
  }
  // LayerNorm per token (results stay in v0/v1)
  #pragma unroll
  for (int tk = 0; tk < 4; ++tk){
    float a = v0[tk], b = v1[tk];
    if (lane >= 48){ a = 0.f; b = 0.f; }
    float mean, rstd;
    ln_butterfly(a, b, mean, rstd);
    v0[tk] = (a - mean)*rstd*gg0 + be0;
    v1[tk] = (b - mean)*rstd*gg1 + be1;
  }

  // ---- phase 2: outputs (qtmp/vres overlay slab; barrier before overlay) --
  if (sec == 0){
    __syncthreads();                              // slab -> qtmp overlay
    #pragma unroll
    for (int tk = 0; tk < 4; ++tk){
      const int n = tok0 + wid*4 + tk;
      const int token = bh*N_ + n;
      if (lane < 48){
        ((u32*)qp)  [(size_t)token*48 + lane] = pack2(v0[tk], v1[tk]);
        ((u32*)Qaug)[(size_t)token*80 + lane] = pack2(v0[tk]*QSCALE_LOG2E, v1[tk]*QSCALE_LOG2E);
        *(float2*)&sm.qtmp[wid][tk][c0] = make_float2(v0[tk], v1[tk]);
      }
    }
    // qtmp written/read by the SAME wave -> ordered by lgkmcnt, no barrier
    #pragma unroll
    for (int tk = 0; tk < 4; ++tk){
      const int n = tok0 + wid*4 + tk;
      const int token = bh*N_ + n;
      if (lane < 36){
        const float* tb; int idx;
        if (lane < 14)      { tb = rph; idx = hh[tk] - lane      + 13; }
        else if (lane < 28) { tb = rpw; idx = ww[tk] - (lane-14) + 13; }
        else                { tb = rpt; idx = tt[tk] - (lane-28) +  7; }
        const float4* t4 = (const float4*)(tb + (size_t)idx*HD_);
        const float4* q4 = (const float4*)&sm.qtmp[wid][tk][0];
        float ap[4] = {0.f, 0.f, 0.f, 0.f};
        #pragma unroll
        for (int i = 0; i < 24; ++i){
          const float4 rv = t4[i];
          const float4 qv = q4[i];                 // ds_read_b128 broadcast
          ap[i & 3] = fmaf(qv.x, rv.x,
                      fmaf(qv.y, rv.y,
                      fmaf(qv.z, rv.z,
                      fmaf(qv.w, rv.w, ap[i & 3]))));
        }
        const float acc = (ap[0] + ap[1]) + (ap[2] + ap[3]);
        Qaug[(size_t)token*CAUG_ + HD_ + lane] = f2b(acc * LOG2E);
      } else {
        Qaug[(size_t)token*CAUG_ + HD_ + lane] = 0;
      }
    }
  } else if (sec == 1){
    // no LDS use in this branch -> no barrier needed
    #pragma unroll
    for (int tk = 0; tk < 4; ++tk){
      const int n = tok0 + wid*4 + tk;
      const int tl = n >> 4, nr = n & 15;
      if (lane < 48){
        const size_t idx = ((((size_t)bh*98 + tl)*5 + (lane>>4))*64
                           + ((lane&15)>>2)*16 + nr)*4 + (lane&3);
        ((u32*)Kt)[idx] = pack2(v0[tk], v1[tk]);
      } else {
        const int m = lane - 48;
        u32 pr_[2];
        #pragma unroll
        for (int h2 = 0; h2 < 2; ++h2){
          u32 w_ = 0;
          #pragma unroll
          for (int e = 0; e < 2; ++e){
            const int jj = 4*m + 2*h2 + e;
            bool on = (jj < 14) ? (jj == hh[tk]) : (jj < 28) ? (jj-14 == ww[tk])
                     : (jj < 36) ? (jj-28 == tt[tk]) : false;
            if (on) w_ |= (0x3F80u << (16*e));
          }
          pr_[h2] = w_;
        }
        const size_t bidx = ((((size_t)bh*98 + tl)*5 + (3 + (m>>3)))*64
                            + ((m&7)>>1)*16 + nr)*4 + 2*(m&1);
        *(uint2*)((u32*)Kt + bidx) = make_uint2(pr_[0], pr_[1]);
      }
    }
  } else {
    __syncthreads();                              // slab -> vres overlay
    #pragma unroll
    for (int tk = 0; tk < 4; ++tk){
      if (lane < 48) sm.vres[wid*4 + tk][lane] = pack2(v0[tk], v1[tk]);
    }
    __syncthreads();
    if (threadIdx.x < 2*HD_){
      const int grp = threadIdx.x / HD_, c = threadIdx.x % HD_;
      const int t0g = grp*8;
      u32 o[4];
      #pragma unroll
      for (int i = 0; i < 4; ++i){
        const u32 a = sm.vres[t0g + 2*i][c>>1], b = sm.vres[t0g + 2*i+1][c>>1];
        const u32 ra = (c&1) ? (a >> 16) : (a & 0xffffu);
        const u32 rb = (c&1) ? (b >> 16) : (b & 0xffffu);
        o[i] = ra | (rb << 16);
      }
      const int n0g = tok0 + t0g;
      const int pr = n0g >> 5, qd = (n0g & 31) >> 3;
      bf_t* dst = Vtt + ((((size_t)bh*49 + pr)*6 + (c>>4))*64 + qd*16 + (c&15))*8;
      *(uint4*)dst = make_uint4(o[0], o[1], o[2], o[3]);
    }
  }
}

// ---------------------------------------------------------------------------
// K4: MFMA flash attention. R20: 32 q-rows/block, 4-wave split-K with K/V
// FRAGMENT REGISTER REUSE: each wave computes TWO q-tiles (A: rows 0-15,
// B: rows 16-31) sharing every K-frag and V-frag load -> K/V L2 traffic
// halves (620 -> 310 MB) and MFMA ILP doubles (2 independent acc chains).
// Blocks 784 -> 392 (8 bh x 49), 256 threads. LDS 36 KB.
// Deferred-max softmax retained (mc=0 until single end-of-loop rescale).
// ---------------------------------------------------------------------------
__global__ __launch_bounds__(256) void k_attn(
    const bf_t* __restrict__ Qaug, const bf_t* __restrict__ Kt,
    const bf_t* __restrict__ Vtt, const bf_t* __restrict__ qp,
    bf_t* __restrict__ attb){
  __shared__ __align__(16) short Pb[4][16][80];   // per wave: 16 rows x (2 tiles x 40)
  __shared__ bf_t Os[4][32][96];                  // per-wave partial O (bf16)
  __shared__ float ms[4][32], ls[4][32];          // per-wave partial m, l
  const int wid = threadIdx.x >> 6, lane = threadIdx.x & 63;
  const int bh = blockIdx.x & 7, qt = blockIdx.x >> 3;   // 392 = 8 x 49
  const int q0 = qt*32;
  const int nl = lane & 15, quad = lane >> 4;

  bf16x8 qaA[5], qaB[5];
  {
    const bf_t* QrowA = Qaug + ((size_t)bh*N_ + q0 + nl)*CAUG_ + quad*8;
    const bf_t* QrowB = QrowA + (size_t)16*CAUG_;
    #pragma unroll
    for (int i = 0; i < 5; ++i){
      qaA[i] = *(const bf16x8*)(QrowA + i*32);
      qaB[i] = *(const bf16x8*)(QrowB + i*32);
    }
  }
  short* Pw = &Pb[wid][0][0];

  f32x4 OA[6], OB[6];
  #pragma unroll
  for (int i = 0; i < 6; ++i){ OA[i] = (f32x4){0.f,0.f,0.f,0.f}; OB[i] = (f32x4){0.f,0.f,0.f,0.f}; }
  float rmaxA[4] = {-3e38f,-3e38f,-3e38f,-3e38f}, lA[4] = {0.f,0.f,0.f,0.f}, mcA[4];
  float rmaxB[4] = {-3e38f,-3e38f,-3e38f,-3e38f}, lB[4] = {0.f,0.f,0.f,0.f}, mcB[4];

  auto s_tile = [&](int tl, int half){
    const bf_t* Kp = Kt + (((size_t)bh*98 + tl)*5*64 + lane)*8;
    f32x4 sA = (f32x4){0.f,0.f,0.f,0.f};
    f32x4 sB = (f32x4){0.f,0.f,0.f,0.f};
    #pragma unroll
    for (int i = 0; i < 5; ++i){
      const bf16x8 kf = *(const bf16x8*)(Kp + i*512);   // shared by A and B
      sA = __builtin_amdgcn_mfma_f32_16x16x32_bf16(qaA[i], kf, sA, 0, 0, 0);
      sB = __builtin_amdgcn_mfma_f32_16x16x32_bf16(qaB[i], kf, sB, 0, 0, 0);
    }
    #pragma unroll
    for (int r = 0; r < 4; ++r){
      rmaxA[r] = fmaxf(rmaxA[r], sA[r]);
      const float pA_ = exp2f(sA[r]);
      lA[r] += pA_;
      Pw[(quad*4 + r)*80 + half*16 + nl] = (short)f2b(pA_);
      rmaxB[r] = fmaxf(rmaxB[r], sB[r]);
      const float pB_ = exp2f(sB[r]);
      lB[r] += pB_;
      Pw[(quad*4 + r)*80 + 40 + half*16 + nl] = (short)f2b(pB_);
    }
  };
  auto rescale = [&](){
    #pragma unroll
    for (int r = 0; r < 4; ++r){
      float tm = rmaxA[r];
      tm = fmaxf(tm, __shfl_xor(tm, 1));
      tm = fmaxf(tm, __shfl_xor(tm, 2));
      tm = fmaxf(tm, __shfl_xor(tm, 4));
      tm = fmaxf(tm, __shfl_xor(tm, 8));
      const float mn = fmaxf(0.f, tm);
      const float al = exp2f(-mn);
      mcA[r] = mn; lA[r] *= al;
      #pragma unroll
      for (int ct = 0; ct < 6; ++ct) OA[ct][r] *= al;
      float tb = rmaxB[r];
      tb = fmaxf(tb, __shfl_xor(tb, 1));
      tb = fmaxf(tb, __shfl_xor(tb, 2));
      tb = fmaxf(tb, __shfl_xor(tb, 4));
      tb = fmaxf(tb, __shfl_xor(tb, 8));
      const float mnb = fmaxf(0.f, tb);
      const float alb = exp2f(-mnb);
      mcB[r] = mnb; lB[r] *= alb;
      #pragma unroll
      for (int ct = 0; ct < 6; ++ct) OB[ct][r] *= alb;
    }
  };

  const int p0 = (wid == 0) ? 0 : (13 + 12*(wid-1));
  const int npairs = (wid == 0) ? 13 : 12;
  #pragma unroll 1
  for (int pi = 0; pi < npairs; ++pi){
    const int kp = p0 + pi;
    s_tile(2*kp,     0);
    s_tile(2*kp + 1, 1);
    const bf16x8 paA = *(const bf16x8*)(Pw + nl*80 + quad*8);
    const bf16x8 paB = *(const bf16x8*)(Pw + nl*80 + 40 + quad*8);
    const bf_t* Vp = Vtt + (((size_t)bh*49 + kp)*6*64 + lane)*8;
    #pragma unroll
    for (int ct = 0; ct < 6; ++ct){
      const bf16x8 vf = *(const bf16x8*)(Vp + ct*512);  // shared by A and B
      OA[ct] = __builtin_amdgcn_mfma_f32_16x16x32_bf16(paA, vf, OA[ct], 0, 0, 0);
      OB[ct] = __builtin_amdgcn_mfma_f32_16x16x32_bf16(paB, vf, OB[ct], 0, 0, 0);
    }
    if (pi == npairs-1) rescale();
  }

  #pragma unroll
  for (int r = 0; r < 4; ++r){
    float la_ = lA[r];
    la_ += __shfl_xor(la_, 1); la_ += __shfl_xor(la_, 2);
    la_ += __shfl_xor(la_, 4); la_ += __shfl_xor(la_, 8);
    float lb_ = lB[r];
    lb_ += __shfl_xor(lb_, 1); lb_ += __shfl_xor(lb_, 2);
    lb_ += __shfl_xor(lb_, 4); lb_ += __shfl_xor(lb_, 8);
    if (nl == 0){
      ms[wid][quad*4 + r]      = mcA[r]; ls[wid][quad*4 + r]      = la_;
      ms[wid][16 + quad*4 + r] = mcB[r]; ls[wid][16 + quad*4 + r] = lb_;
    }
    #pragma unroll
    for (int ct = 0; ct < 6; ++ct){
      Os[wid][quad*4 + r][ct*16 + nl]      = f2b(OA[ct][r]);
      Os[wid][16 + quad*4 + r][ct*16 + nl] = f2b(OB[ct][r]);
    }
  }
  __syncthreads();

  const int bb = bh >> 2, head = bh & 3;
  const int grow0 = bb*N_ + q0;                   // multiple of 32
  for (int e = threadIdx.x; e < 32*96; e += 256){
    const int row = e / 96, col = e % 96;
    float mx = -3e38f;
    #pragma unroll
    for (int w = 0; w < 4; ++w) mx = fmaxf(mx, ms[w][row]);
    float L = 0.f, A = 0.f;
    #pragma unroll
    for (int w = 0; w < 4; ++w){
      const float wt = exp2f(ms[w][row] - mx);
      L += wt*ls[w][row];
      A += wt*b2f(Os[w][row][col]);
    }
    const float val = A/L + b2f(qp[((size_t)bh*N_ + q0 + row)*HD_ + col]);
    attb[ftidx(grow0 + row, head*HD_ + col)] = f2b(val);
  }
}

// ---------------------------------------------------------------------------
// K5: output projection via MFMA, fragment-tiled A (attb) and B (Wpt).
// ---------------------------------------------------------------------------
__global__ __launch_bounds__(256) void k_proj(const bf_t* __restrict__ At,
    const bf_t* __restrict__ Wpt, const float* __restrict__ pb,
    float* __restrict__ out){
  const int wid = threadIdx.x >> 6, lane = threadIdx.x & 63;
  const int wr = wid & 1, wc = wid >> 1;
  const int nl = lane & 15, quad = lane >> 4;
  const int r0 = blockIdx.x*64 + wr*32;
  const int mt0 = r0 >> 4;
  const int nt0 = blockIdx.y*8 + wc*4;
  f32x4 acc[2][4];
  #pragma unroll
  for (int i = 0; i < 2; ++i)
    #pragma unroll
    for (int j = 0; j < 4; ++j) acc[i][j] = (f32x4){0.f,0.f,0.f,0.f};
  const bf_t* A0 = At  + ((size_t)mt0*12*64 + lane)*8;
  const bf_t* B0 = Wpt + ((size_t)nt0*12*64 + lane)*8;
  #pragma unroll 2
  for (int k0 = 0; k0 < 12; ++k0){
    const bf16x8 a0 = *(const bf16x8*)(A0 + k0*512);
    const bf16x8 a1 = *(const bf16x8*)(A0 + 12*512 + k0*512);
    bf16x8 bf[4];
    #pragma unroll
    for (int j = 0; j < 4; ++j) bf[j] = *(const bf16x8*)(B0 + (size_t)(j*12 + k0)*512);
    #pragma unroll
    for (int j = 0; j < 4; ++j){
      acc[0][j] = __builtin_amdgcn_mfma_f32_16x16x32_bf16(a0, bf[j], acc[0][j], 0, 0, 0);
      acc[1][j] = __builtin_amdgcn_mfma_f32_16x16x32_bf16(a1, bf[j], acc[1][j], 0, 0, 0);
    }
  }
  #pragma unroll
  for (int i = 0; i < 2; ++i){
    #pragma unroll
    for (int r = 0; r < 4; ++r){
      const int m = r0 + i*16 + quad*4 + r;
      #pragma unroll
      for (int j = 0; j < 4; ++j){
        const int col = (nt0 + j)*16 + nl;
        out[(size_t)m*DIM_ + col] = acc[i][j][r] + pb[col];
      }
    }
  }
}

// ---------------------------------------------------------------------------
extern "C" void kernel_launch(void* const* d_in, const int* in_sizes, int n_in,
                              void* d_out, int out_size, void* d_ws, size_t ws_size,
                              hipStream_t stream){
  const float* x      = (const float*)d_in[0];
  const float* qkv_w  = (const float*)d_in[1];
  const float* proj_w = (const float*)d_in[2];
  const float* proj_b = (const float*)d_in[3];
  const float* pqw    = (const float*)d_in[4];
  const float* pkw    = (const float*)d_in[5];
  const float* pvw    = (const float*)d_in[6];
  const float* nqw    = (const float*)d_in[7];
  const float* nqb    = (const float*)d_in[8];
  const float* nkw    = (const float*)d_in[9];
  const float* nkb    = (const float*)d_in[10];
  const float* nvw    = (const float*)d_in[11];
  const float* nvb    = (const float*)d_in[12];
  const float* rph    = (const float*)d_in[13];
  const float* rpw    = (const float*)d_in[14];
  const float* rpt    = (const float*)d_in[15];

  // Workspace (bytes), ~23.7 MB total. attb overlays raw_q after pooling.
  char* p = (char*)d_ws;
  const size_t RAW = (size_t)BH_*N_*HD_*2;       // 2,408,448 B
  const size_t AUG = (size_t)BH_*N_*CAUG_*2;     // 4,014,080 B
  bf_t* xb     = (bf_t*)(p);                     // frag-tiled
  bf_t* wqkvb  = (bf_t*)(p + RAW);               // frag-tiled
  bf_t* wprojb = (bf_t*)(p + RAW + 884736);      // frag-tiled
  char* p2 = p + RAW + 884736 + 294912;
  bf_t* raw_q  = (bf_t*)(p2);
  bf_t* raw_k  = (bf_t*)(p2 + RAW);
  bf_t* raw_v  = (bf_t*)(p2 + 2*RAW);
  bf_t* attb   = raw_q;                          // overlays raw_q (frag-tiled)
  bf_t* qp     = (bf_t*)(p2 + 3*RAW);
  bf_t* Qaug   = (bf_t*)(p2 + 4*RAW);
  bf_t* Kt     = (bf_t*)(p2 + 4*RAW + AUG);      // tiled Kaug
  bf_t* Vtt    = (bf_t*)(p2 + 4*RAW + 2*AUG);    // tiled V
  float* wtq   = (float*)(p2 + 4*RAW + 2*AUG + RAW);   // 3 x 27x96 fp32
  float* wtk   = wtq + 27*HD_;
  float* wtv   = wtk + 27*HD_;

  k_cast     <<<CAST_BLOCKS + 31, 256, 0, stream>>>(x, xb, qkv_w, wqkvb, proj_w, wprojb,
                                                    pqw, pkw, pvw, wtq, wtk, wtv);
  k_qkv      <<<dim3(BN_/64, 9),  256, 0, stream>>>(xb, wqkvb, raw_q, raw_k, raw_v);
  k_pool_slab<<<3*784,            256, 0, stream>>>(raw_q, raw_k, raw_v,
                                                    wtq, wtk, wtv,
                                                    nqw, nqb, nkw, nkb, nvw, nvb,
                                                    rph, rpw, rpt,
                                                    qp, Qaug, Kt, Vtt);
  k_attn     <<<BH_*49,           256, 0, stream>>>(Qaug, Kt, Vtt, qp, attb);
  k_proj     <<<dim3(BN_/64, 3),  256, 0, stream>>>(attb, wprojb, proj_b, (float*)d_out);
}

// Round 9
// 195.099 us; speedup vs baseline: 1.0010x; 1.0010x over previous
//
#include <hip/hip_runtime.h>

// Problem constants (fixed by reference)
#define B_    2
#define NH_   4
#define T_    8
#define H_    14
#define W_    14
#define HW_   196             // H*W
#define HD_   96
#define DIM_  384
#define N_    1568            // T*H*W
#define BH_   (B_*NH_)        // 8
#define BN_   (B_*N_)         // 3136
#define BHN_  (BH_*N_)        // 12544
#define CAUG_ 160             // 96 + 36 one-hot/bias + 28 pad

typedef unsigned short bf_t;
typedef unsigned int   u32;
typedef __attribute__((ext_vector_type(8))) short bf16x8;
typedef __attribute__((ext_vector_type(4))) float f32x4;

#define LOG2E 1.4426950408889634f
#define QSCALE_LOG2E 0.14724445f   /* 96^-0.5 * log2(e) */

static __device__ __forceinline__ float lo16(u32 v){ union{u32 i; float f;}x; x.i = v<<16;           return x.f; }
static __device__ __forceinline__ float hi16(u32 v){ union{u32 i; float f;}x; x.i = v & 0xffff0000u; return x.f; }
static __device__ __forceinline__ float b2f(bf_t v){ union{u32 i; float f;}x; x.i = ((u32)v)<<16;    return x.f; }
static __device__ __forceinline__ bf_t  f2b(float f){
  union{float f; u32 i;} x; x.f = f;
  return (bf_t)((x.i + 0x7fffu + ((x.i>>16)&1u)) >> 16);   // RNE
}
static __device__ __forceinline__ u32 pack2(float a, float b){
  return (u32)f2b(a) | ((u32)f2b(b) << 16);
}
// fragment-tile index for a row-major [R][384] matrix element (row, k)
static __device__ __forceinline__ size_t ftidx(int row, int k){
  return ((((size_t)(row>>4))*12 + (k>>5))*64 + ((k>>3)&3)*16 + (row&15))*8 + (k&7);
}

// ---------------------------------------------------------------------------
// K0: cast x / qkv_w / proj_w fp32 -> bf16 in FRAGMENT-TILED layout, plus
// conv-weight transpose [96][27]->[27][96] fp32 (last 31 blocks).
// ---------------------------------------------------------------------------
#define NA_ (BN_*DIM_)        // 1,204,224
#define NB_ (3*DIM_*DIM_)     //   442,368
#define NC_ (DIM_*DIM_)       //   147,456
#define CAST_BLOCKS ((NA_+NB_+NC_)/4/256)   // 1752 exactly

__global__ __launch_bounds__(256) void k_cast(
    const float* __restrict__ a, bf_t* __restrict__ ad,
    const float* __restrict__ b, bf_t* __restrict__ bd,
    const float* __restrict__ c, bf_t* __restrict__ cd,
    const float* __restrict__ wq, const float* __restrict__ wk,
    const float* __restrict__ wv, float* __restrict__ tq,
    float* __restrict__ tk, float* __restrict__ tv){
  if (blockIdx.x < CAST_BLOCKS){
    const int i = blockIdx.x*256 + threadIdx.x;     // float4 index
    const int i4 = i*4;
    float4 v; bf_t* dst; int row, k;
    if (i4 < NA_){
      v = ((const float4*)a)[i];
      dst = ad; row = i4/DIM_; k = i4%DIM_;
    } else if (i4 < NA_+NB_){
      const int f = i4 - NA_;
      v = ((const float4*)b)[i - NA_/4];
      dst = bd; row = f/DIM_; k = f%DIM_;
    } else {
      const int f = i4 - NA_ - NB_;
      v = ((const float4*)c)[i - (NA_+NB_)/4];
      dst = cd; row = f/DIM_; k = f%DIM_;
    }
    ushort4 o; o.x = f2b(v.x); o.y = f2b(v.y); o.z = f2b(v.z); o.w = f2b(v.w);
    *(ushort4*)(dst + ftidx(row, k)) = o;           // k%4==0 -> 8B aligned
  } else {
    const int idx = (blockIdx.x - CAST_BLOCKS)*256 + threadIdx.x;
    if (idx >= 3*HD_*27) return;
    const int t = idx / (HD_*27), rem = idx % (HD_*27);
    const int ch = rem / 27, j = rem % 27;
    const float* s = (t==0)? wq : (t==1)? wk : wv;
    float* d       = (t==0)? tq : (t==1)? tk : tv;
    d[j*HD_ + ch] = s[ch*27 + j];
  }
}

// ---------------------------------------------------------------------------
// K1: QKV GEMM via MFMA, fragment-tiled operands.
// R21: LDS-staged epilogue. Old: 32 scalar 2B global stores/thread, each
// with a recomputed /384,/96 div-chain (~320 VALU). New: MFMA frags ->
// LDS tile [64][136] (pad kills quad-row bank alias), barrier, then each
// thread writes 4x uint4 coalesced (every 32-col segment lies in ONE
// head/s plane since gcd(128,96)=32).
// ---------------------------------------------------------------------------
__global__ __launch_bounds__(256) void k_qkv(const bf_t* __restrict__ Xt,
    const bf_t* __restrict__ Wt,
    bf_t* __restrict__ q, bf_t* __restrict__ k, bf_t* __restrict__ v){
  __shared__ __align__(16) bf_t tile[64][136];
  const int wid = threadIdx.x >> 6, lane = threadIdx.x & 63;
  const int wr = wid & 1, wc = wid >> 1;
  const int nl = lane & 15, quad = lane >> 4;
  const int r0 = blockIdx.x*64 + wr*32;
  const int mt0 = r0 >> 4;
  const int nt0 = blockIdx.y*8 + wc*4;
  f32x4 acc[2][4];
  #pragma unroll
  for (int i = 0; i < 2; ++i)
    #pragma unroll
    for (int j = 0; j < 4; ++j) acc[i][j] = (f32x4){0.f,0.f,0.f,0.f};
  const bf_t* A0 = Xt + ((size_t)mt0*12*64 + lane)*8;
  const bf_t* B0 = Wt + ((size_t)nt0*12*64 + lane)*8;
  #pragma unroll 2
  for (int k0 = 0; k0 < 12; ++k0){
    const bf16x8 a0 = *(const bf16x8*)(A0 + k0*512);
    const bf16x8 a1 = *(const bf16x8*)(A0 + 12*512 + k0*512);
    bf16x8 bf[4];
    #pragma unroll
    for (int j = 0; j < 4; ++j) bf[j] = *(const bf16x8*)(B0 + (size_t)(j*12 + k0)*512);
    #pragma unroll
    for (int j = 0; j < 4; ++j){
      acc[0][j] = __builtin_amdgcn_mfma_f32_16x16x32_bf16(a0, bf[j], acc[0][j], 0, 0, 0);
      acc[1][j] = __builtin_amdgcn_mfma_f32_16x16x32_bf16(a1, bf[j], acc[1][j], 0, 0, 0);
    }
  }
  // frags -> LDS tile (local row = wr*32+i*16+quad*4+r, local col = wc*64+j*16+nl)
  #pragma unroll
  for (int i = 0; i < 2; ++i)
    #pragma unroll
    for (int r = 0; r < 4; ++r){
      const int lrow = wr*32 + i*16 + quad*4 + r;
      #pragma unroll
      for (int j = 0; j < 4; ++j)
        tile[lrow][wc*64 + j*16 + nl] = f2b(acc[i][j][r]);
    }
  __syncthreads();
  // coalesced store: thread t -> row t>>2, 32-col segment (t&3)*32
  {
    const int row = threadIdx.x >> 2, seg = threadIdx.x & 3;
    const int m  = blockIdx.x*64 + row;
    const int bb = m / N_, nn = m % N_;
    const int cg0 = blockIdx.y*128 + seg*32;      // global col of segment start
    const int s    = cg0 / DIM_;
    const int remS = cg0 - s*DIM_;
    const int head = remS / HD_, hc0 = remS % HD_;   // segment fits one plane
    bf_t* dst = ((s==0) ? q : (s==1) ? k : v)
              + ((size_t)(bb*NH_ + head)*N_ + nn)*HD_ + hc0;
    #pragma unroll
    for (int kk = 0; kk < 4; ++kk)
      *(uint4*)(dst + kk*8) = *(const uint4*)&tile[row][seg*32 + kk*8];
  }
}

static __device__ __forceinline__ void ln_butterfly(
    float v0, float v1, float& mean, float& rstd){
  float s  = v0 + v1;
  float s2 = v0*v0 + v1*v1;
  #pragma unroll
  for (int off = 32; off > 0; off >>= 1){
    s  += __shfl_xor(s,  off);
    s2 += __shfl_xor(s2, off);
  }
  mean = s * (1.f/HD_);
  const float var = fmaxf(s2*(1.f/HD_) - mean*mean, 0.f);
  rstd = rsqrtf(var + 1e-6f);
}

// ---------------------------------------------------------------------------
// K2: LDS-slab pooled conv+LN, 16 tokens/block (4 waves x 4 tokens).
// Halo slab 162 rows (3t x 3h x 18w) x 96ch bf16 = 31.1 KB.
// R19 decode retained: bh = blockIdx.x & 7 (XCD-pinned; FETCH 22.2->3.9 MB
// verified). Compute structure = R16 (proven best at ~48 us).
// ---------------------------------------------------------------------------
union PoolSM {
  bf_t  slab[162][HD_];       // 31,104 B  (phase 1)
  float qtmp[4][4][HD_];      //  6,144 B  (phase 2, sec 0; per-wave)
  u32   vres[16][48];         //  3,072 B  (phase 2, sec 2)
};

__global__ __launch_bounds__(256) void k_pool_slab(
    const bf_t* __restrict__ qr_, const bf_t* __restrict__ kr_, const bf_t* __restrict__ vr_,
    const float* __restrict__ wtq, const float* __restrict__ wtk, const float* __restrict__ wtv,
    const float* __restrict__ gq, const float* __restrict__ bq,
    const float* __restrict__ gk, const float* __restrict__ bk,
    const float* __restrict__ gv, const float* __restrict__ bv,
    const float* __restrict__ rph, const float* __restrict__ rpw,
    const float* __restrict__ rpt,
    bf_t* __restrict__ qp, bf_t* __restrict__ Qaug,
    bf_t* __restrict__ Kt, bf_t* __restrict__ Vtt){
  __shared__ __align__(16) PoolSM sm;
  const int wid = threadIdx.x >> 6, lane = threadIdx.x & 63;
  const int bh   = blockIdx.x & 7;          // XCD-pinned (2352 = 8 x 294)
  const int rest = blockIdx.x >> 3;
  const int sec  = rest / 98;
  const int tok0 = (rest % 98)*16;
  const bf_t*  src = (sec==0)? qr_ : (sec==1)? kr_ : vr_;
  const float* wt  = (sec==0)? wtq : (sec==1)? wtk : wtv;
  const float* g   = (sec==0)? gq  : (sec==1)? gk  : gv;
  const float* be  = (sec==0)? bq  : (sec==1)? bk  : bv;
  const bf_t* base = src + (size_t)bh*N_*HD_;

  // per-lane channel pair; first weight trio + LN params overlap staging
  const int c0 = (lane < 48) ? 2*lane : 0;
  float2 wcur[3], wnxt[3];
  #pragma unroll
  for (int dw = 0; dw < 3; ++dw) wcur[dw] = *(const float2*)(wt + dw*HD_ + c0);
  const float gg0 = g[c0], gg1 = g[c0+1], be0 = be[c0], be1 = be[c0+1];

  // ---- staging: batched loads into regs, then LDS writes (vmcnt pipeline) --
  {
    uint4 stg[8];
    #pragma unroll
    for (int it = 0; it < 8; ++it){
      const int li = threadIdx.x + it*256;
      const int lc = (li < 162*12) ? li : (162*12 - 1);
      const int rw = lc / 12, ss = lc % 12;
      const int aa = rw/54, bb2 = (rw%54)/18, cc = rw%18;
      int nn = tok0 + (aa-1)*HW_ + (bb2-1)*W_ + (cc-1);
      nn = min(max(nn, 0), N_-1);
      stg[it] = *(const uint4*)(base + (size_t)nn*HD_ + ss*8);
    }
    #pragma unroll
    for (int it = 0; it < 8; ++it){
      const int li = threadIdx.x + it*256;
      if (li < 162*12){
        const int rw = li / 12, ss = li % 12;
        *(uint4*)&sm.slab[rw][ss*8] = stg[it];
      }
    }
  }
  __syncthreads();

  // token coordinates (wave-uniform) + 27-bit validity masks
  int tt[4], hh[4], ww[4];
  u32 mr[4];
  #pragma unroll
  for (int tk = 0; tk < 4; ++tk){
    const int n = tok0 + wid*4 + tk;
    tt[tk] = n / HW_;
    const int rm = n % HW_;
    hh[tk] = rm / W_; ww[tk] = rm % W_;
    const u32 wb = (ww[tk] > 0 ? 1u : 0u) | 2u | (ww[tk] < W_-1 ? 4u : 0u);
    const u32 h9 = (hh[tk] > 0 ? wb : 0u) | (wb << 3) | (hh[tk] < H_-1 ? (wb << 6) : 0u);
    mr[tk] = (tt[tk] > 0 ? h9 : 0u) | (h9 << 9) | (tt[tk] < T_-1 ? (h9 << 18) : 0u);
  }

  // ---- phase 1: conv, software-pipelined row reads ----
  float v0[4] = {0.f,0.f,0.f,0.f}, v1[4] = {0.f,0.f,0.f,0.f};
  u32 rr[6], rrn[6];
  #pragma unroll
  for (int s = 0; s < 6; ++s) rr[s] = *(const u32*)&sm.slab[wid*4 + s][c0];
  #pragma unroll 1
  for (int j9 = 0; j9 < 9; ++j9){
    if (j9 < 8){
      const int jn = j9 + 1;
      const int rbn = (jn/3)*54 + (jn%3)*18 + wid*4;
      #pragma unroll
      for (int s = 0; s < 6; ++s) rrn[s] = *(const u32*)&sm.slab[rbn + s][c0];
      #pragma unroll
      for (int dw = 0; dw < 3; ++dw)
        wnxt[dw] = *(const float2*)(wt + (jn*3 + dw)*HD_ + c0);
    }
    #pragma unroll
    for (int tk = 0; tk < 4; ++tk){
      #pragma unroll
      for (int dw = 0; dw < 3; ++dw){
        const u32 d = (mr[tk] & (1u << dw)) ? rr[tk+dw] : 0u;
        v0[tk] = fmaf(wcur[dw].x, lo16(d), v0[tk]);
        v1[tk] = fmaf(wcur[dw].y, hi16(d), v1[tk]);
      }
      mr[tk] >>= 3;
    }
    #pragma unroll
    for (int s = 0; s < 6; ++s) rr[s] = rrn[s];
    #pragma unroll
    for (int dw = 0; dw < 3; ++dw) wcur[dw] = wnxt[dw];
  }
  // LayerNorm per token (results stay in v0/v1)
  #pragma unroll
  for (int tk = 0; tk < 4; ++tk){
    float a = v0[tk], b = v1[tk];
    if (lane >= 48){ a = 0.f; b = 0.f; }
    float mean, rstd;
    ln_butterfly(a, b, mean, rstd);
    v0[tk] = (a - mean)*rstd*gg0 + be0;
    v1[tk] = (b - mean)*rstd*gg1 + be1;
  }

  // ---- phase 2: outputs (qtmp/vres overlay slab; barrier before overlay) --
  if (sec == 0){
    __syncthreads();                              // slab -> qtmp overlay
    #pragma unroll
    for (int tk = 0; tk < 4; ++tk){
      const int n = tok0 + wid*4 + tk;
      const int token = bh*N_ + n;
      if (lane < 48){
        ((u32*)qp)  [(size_t)token*48 + lane] = pack2(v0[tk], v1[tk]);
        ((u32*)Qaug)[(size_t)token*80 + lane] = pack2(v0[tk]*QSCALE_LOG2E, v1[tk]*QSCALE_LOG2E);
        *(float2*)&sm.qtmp[wid][tk][c0] = make_float2(v0[tk], v1[tk]);
      }
    }
    // qtmp written/read by the SAME wave -> ordered by lgkmcnt, no barrier
    #pragma unroll
    for (int tk = 0; tk < 4; ++tk){
      const int n = tok0 + wid*4 + tk;
      const int token = bh*N_ + n;
      if (lane < 36){
        const float* tb; int idx;
        if (lane < 14)      { tb = rph; idx = hh[tk] - lane      + 13; }
        else if (lane < 28) { tb = rpw; idx = ww[tk] - (lane-14) + 13; }
        else                { tb = rpt; idx = tt[tk] - (lane-28) +  7; }
        const float4* t4 = (const float4*)(tb + (size_t)idx*HD_);
        const float4* q4 = (const float4*)&sm.qtmp[wid][tk][0];
        float ap[4] = {0.f, 0.f, 0.f, 0.f};
        #pragma unroll
        for (int i = 0; i < 24; ++i){
          const float4 rv = t4[i];
          const float4 qv = q4[i];                 // ds_read_b128 broadcast
          ap[i & 3] = fmaf(qv.x, rv.x,
                      fmaf(qv.y, rv.y,
                      fmaf(qv.z, rv.z,
                      fmaf(qv.w, rv.w, ap[i & 3]))));
        }
        const float acc = (ap[0] + ap[1]) + (ap[2] + ap[3]);
        Qaug[(size_t)token*CAUG_ + HD_ + lane] = f2b(acc * LOG2E);
      } else {
        Qaug[(size_t)token*CAUG_ + HD_ + lane] = 0;
      }
    }
  } else if (sec == 1){
    // no LDS use in this branch -> no barrier needed
    #pragma unroll
    for (int tk = 0; tk < 4; ++tk){
      const int n = tok0 + wid*4 + tk;
      const int tl = n >> 4, nr = n & 15;
      if (lane < 48){
        const size_t idx = ((((size_t)bh*98 + tl)*5 + (lane>>4))*64
                           + ((lane&15)>>2)*16 + nr)*4 + (lane&3);
        ((u32*)Kt)[idx] = pack2(v0[tk], v1[tk]);
      } else {
        const int m = lane - 48;
        u32 pr_[2];
        #pragma unroll
        for (int h2 = 0; h2 < 2; ++h2){
          u32 w_ = 0;
          #pragma unroll
          for (int e = 0; e < 2; ++e){
            const int jj = 4*m + 2*h2 + e;
            bool on = (jj < 14) ? (jj == hh[tk]) : (jj < 28) ? (jj-14 == ww[tk])
                     : (jj < 36) ? (jj-28 == tt[tk]) : false;
            if (on) w_ |= (0x3F80u << (16*e));
          }
          pr_[h2] = w_;
        }
        const size_t bidx = ((((size_t)bh*98 + tl)*5 + (3 + (m>>3)))*64
                            + ((m&7)>>1)*16 + nr)*4 + 2*(m&1);
        *(uint2*)((u32*)Kt + bidx) = make_uint2(pr_[0], pr_[1]);
      }
    }
  } else {
    __syncthreads();                              // slab -> vres overlay
    #pragma unroll
    for (int tk = 0; tk < 4; ++tk){
      if (lane < 48) sm.vres[wid*4 + tk][lane] = pack2(v0[tk], v1[tk]);
    }
    __syncthreads();
    if (threadIdx.x < 2*HD_){
      const int grp = threadIdx.x / HD_, c = threadIdx.x % HD_;
      const int t0g = grp*8;
      u32 o[4];
      #pragma unroll
      for (int i = 0; i < 4; ++i){
        const u32 a = sm.vres[t0g + 2*i][c>>1], b = sm.vres[t0g + 2*i+1][c>>1];
        const u32 ra = (c&1) ? (a >> 16) : (a & 0xffffu);
        const u32 rb = (c&1) ? (b >> 16) : (b & 0xffffu);
        o[i] = ra | (rb << 16);
      }
      const int n0g = tok0 + t0g;
      const int pr = n0g >> 5, qd = (n0g & 31) >> 3;
      bf_t* dst = Vtt + ((((size_t)bh*49 + pr)*6 + (c>>4))*64 + qd*16 + (c&15))*8;
      *(uint4*)dst = make_uint4(o[0], o[1], o[2], o[3]);
    }
  }
}

// ---------------------------------------------------------------------------
// K4: MFMA flash attention, 8-wave in-block split-K, fragment-tiled K/V
// (R19 proven form; R20's 2-q-tile variant halved occupancy and regressed).
// bh = blockIdx.x & 7 pins each (batch,head)'s 98 q-tile blocks to one XCD.
// ---------------------------------------------------------------------------
__global__ __launch_bounds__(512) void k_attn(
    const bf_t* __restrict__ Qaug, const bf_t* __restrict__ Kt,
    const bf_t* __restrict__ Vtt, const bf_t* __restrict__ qp,
    bf_t* __restrict__ attb){
  __shared__ __align__(16) short Pb[8][16][40];   // per-wave P tile (+8 pad)
  __shared__ bf_t Os[8][16][96];                  // per-wave partial O (bf16)
  __shared__ float ms[8][16], ls[8][16];          // per-wave partial m, l
  const int wid = threadIdx.x >> 6, lane = threadIdx.x & 63;
  const int bh = blockIdx.x & 7, qt = blockIdx.x >> 3;   // XCD-aware (784=8x98)
  const int q0 = qt*16;
  const int nl = lane & 15, quad = lane >> 4;

  bf16x8 qa[5];
  {
    const bf_t* Qrow = Qaug + ((size_t)bh*N_ + q0 + nl)*CAUG_ + quad*8;
    #pragma unroll
    for (int i = 0; i < 5; ++i) qa[i] = *(const bf16x8*)(Qrow + i*32);
  }
  short* Pw = &Pb[wid][0][0];

  f32x4 O[6];
  #pragma unroll
  for (int i = 0; i < 6; ++i) O[i] = (f32x4){0.f,0.f,0.f,0.f};
  float mc[4]   = {0.f,0.f,0.f,0.f};
  float rmax[4] = {-3e38f,-3e38f,-3e38f,-3e38f};
  float l[4]    = {0.f,0.f,0.f,0.f};

  auto s_tile = [&](int tl, int half){
    const bf_t* Kp = Kt + (((size_t)bh*98 + tl)*5*64 + lane)*8;
    f32x4 s = (f32x4){0.f,0.f,0.f,0.f};
    #pragma unroll
    for (int i = 0; i < 5; ++i)
      s = __builtin_amdgcn_mfma_f32_16x16x32_bf16(qa[i], *(const bf16x8*)(Kp + i*512), s, 0, 0, 0);
    #pragma unroll
    for (int r = 0; r < 4; ++r){
      rmax[r] = fmaxf(rmax[r], s[r]);
      const float p = exp2f(s[r] - mc[r]);
      l[r] += p;
      Pw[(quad*4 + r)*40 + half*16 + nl] = (short)f2b(p);
    }
  };
  auto rescale = [&](){
    #pragma unroll
    for (int r = 0; r < 4; ++r){
      float tm = rmax[r];
      tm = fmaxf(tm, __shfl_xor(tm, 1));
      tm = fmaxf(tm, __shfl_xor(tm, 2));
      tm = fmaxf(tm, __shfl_xor(tm, 4));
      tm = fmaxf(tm, __shfl_xor(tm, 8));
      const float mn = fmaxf(mc[r], tm);
      const float al = exp2f(mc[r] - mn);
      mc[r] = mn; l[r] *= al;
      #pragma unroll
      for (int ct = 0; ct < 6; ++ct) O[ct][r] *= al;
    }
  };

  const int p0 = (wid == 0) ? 0 : (7 + 6*(wid-1));
  const int npairs = (wid == 0) ? 7 : 6;
  #pragma unroll 1
  for (int pi = 0; pi < npairs; ++pi){
    const int kp = p0 + pi;
    s_tile(2*kp,     0);
    s_tile(2*kp + 1, 1);
    const bf16x8 pa = *(const bf16x8*)(Pw + nl*40 + quad*8);
    const bf_t* Vp = Vtt + (((size_t)bh*49 + kp)*6*64 + lane)*8;
    #pragma unroll
    for (int ct = 0; ct < 6; ++ct)
      O[ct] = __builtin_amdgcn_mfma_f32_16x16x32_bf16(pa, *(const bf16x8*)(Vp + ct*512), O[ct], 0, 0, 0);
    if (pi == npairs-1) rescale();
  }

  #pragma unroll
  for (int r = 0; r < 4; ++r){
    float ls_ = l[r];
    ls_ += __shfl_xor(ls_, 1); ls_ += __shfl_xor(ls_, 2);
    ls_ += __shfl_xor(ls_, 4); ls_ += __shfl_xor(ls_, 8);
    if (nl == 0){ ms[wid][quad*4 + r] = mc[r]; ls[wid][quad*4 + r] = ls_; }
    #pragma unroll
    for (int ct = 0; ct < 6; ++ct) Os[wid][quad*4 + r][ct*16 + nl] = f2b(O[ct][r]);
  }
  __syncthreads();

  const int bb = bh >> 2, head = bh & 3;
  const int grow0 = bb*N_ + q0;                   // multiple of 16
  for (int e = threadIdx.x; e < 16*96; e += 512){
    const int row = e / 96, col = e % 96;
    float mx = -3e38f;
    #pragma unroll
    for (int w = 0; w < 8; ++w) mx = fmaxf(mx, ms[w][row]);
    float L = 0.f, A = 0.f;
    #pragma unroll
    for (int w = 0; w < 8; ++w){
      const float wt = exp2f(ms[w][row] - mx);
      L += wt*ls[w][row];
      A += wt*b2f(Os[w][row][col]);
    }
    const float val = A/L + b2f(qp[((size_t)bh*N_ + q0 + row)*HD_ + col]);
    attb[ftidx(grow0 + row, head*HD_ + col)] = f2b(val);
  }
}

// ---------------------------------------------------------------------------
// K5: output projection via MFMA, fragment-tiled A (attb) and B (Wpt).
// ---------------------------------------------------------------------------
__global__ __launch_bounds__(256) void k_proj(const bf_t* __restrict__ At,
    const bf_t* __restrict__ Wpt, const float* __restrict__ pb,
    float* __restrict__ out){
  const int wid = threadIdx.x >> 6, lane = threadIdx.x & 63;
  const int wr = wid & 1, wc = wid >> 1;
  const int nl = lane & 15, quad = lane >> 4;
  const int r0 = blockIdx.x*64 + wr*32;
  const int mt0 = r0 >> 4;
  const int nt0 = blockIdx.y*8 + wc*4;
  f32x4 acc[2][4];
  #pragma unroll
  for (int i = 0; i < 2; ++i)
    #pragma unroll
    for (int j = 0; j < 4; ++j) acc[i][j] = (f32x4){0.f,0.f,0.f,0.f};
  const bf_t* A0 = At  + ((size_t)mt0*12*64 + lane)*8;
  const bf_t* B0 = Wpt + ((size_t)nt0*12*64 + lane)*8;
  #pragma unroll 2
  for (int k0 = 0; k0 < 12; ++k0){
    const bf16x8 a0 = *(const bf16x8*)(A0 + k0*512);
    const bf16x8 a1 = *(const bf16x8*)(A0 + 12*512 + k0*512);
    bf16x8 bf[4];
    #pragma unroll
    for (int j = 0; j < 4; ++j) bf[j] = *(const bf16x8*)(B0 + (size_t)(j*12 + k0)*512);
    #pragma unroll
    for (int j = 0; j < 4; ++j){
      acc[0][j] = __builtin_amdgcn_mfma_f32_16x16x32_bf16(a0, bf[j], acc[0][j], 0, 0, 0);
      acc[1][j] = __builtin_amdgcn_mfma_f32_16x16x32_bf16(a1, bf[j], acc[1][j], 0, 0, 0);
    }
  }
  #pragma unroll
  for (int i = 0; i < 2; ++i){
    #pragma unroll
    for (int r = 0; r < 4; ++r){
      const int m = r0 + i*16 + quad*4 + r;
      #pragma unroll
      for (int j = 0; j < 4; ++j){
        const int col = (nt0 + j)*16 + nl;
        out[(size_t)m*DIM_ + col] = acc[i][j][r] + pb[col];
      }
    }
  }
}

// ---------------------------------------------------------------------------
extern "C" void kernel_launch(void* const* d_in, const int* in_sizes, int n_in,
                              void* d_out, int out_size, void* d_ws, size_t ws_size,
                              hipStream_t stream){
  const float* x      = (const float*)d_in[0];
  const float* qkv_w  = (const float*)d_in[1];
  const float* proj_w = (const float*)d_in[2];
  const float* proj_b = (const float*)d_in[3];
  const float* pqw    = (const float*)d_in[4];
  const float* pkw    = (const float*)d_in[5];
  const float* pvw    = (const float*)d_in[6];
  const float* nqw    = (const float*)d_in[7];
  const float* nqb    = (const float*)d_in[8];
  const float* nkw    = (const float*)d_in[9];
  const float* nkb    = (const float*)d_in[10];
  const float* nvw    = (const float*)d_in[11];
  const float* nvb    = (const float*)d_in[12];
  const float* rph    = (const float*)d_in[13];
  const float* rpw    = (const float*)d_in[14];
  const float* rpt    = (const float*)d_in[15];

  // Workspace (bytes), ~23.7 MB total. attb overlays raw_q after pooling.
  char* p = (char*)d_ws;
  const size_t RAW = (size_t)BH_*N_*HD_*2;       // 2,408,448 B
  const size_t AUG = (size_t)BH_*N_*CAUG_*2;     // 4,014,080 B
  bf_t* xb     = (bf_t*)(p);                     // frag-tiled
  bf_t* wqkvb  = (bf_t*)(p + RAW);               // frag-tiled
  bf_t* wprojb = (bf_t*)(p + RAW + 884736);      // frag-tiled
  char* p2 = p + RAW + 884736 + 294912;
  bf_t* raw_q  = (bf_t*)(p2);
  bf_t* raw_k  = (bf_t*)(p2 + RAW);
  bf_t* raw_v  = (bf_t*)(p2 + 2*RAW);
  bf_t* attb   = raw_q;                          // overlays raw_q (frag-tiled)
  bf_t* qp     = (bf_t*)(p2 + 3*RAW);
  bf_t* Qaug   = (bf_t*)(p2 + 4*RAW);
  bf_t* Kt     = (bf_t*)(p2 + 4*RAW + AUG);      // tiled Kaug
  bf_t* Vtt    = (bf_t*)(p2 + 4*RAW + 2*AUG);    // tiled V
  float* wtq   = (float*)(p2 + 4*RAW + 2*AUG + RAW);   // 3 x 27x96 fp32
  float* wtk   = wtq + 27*HD_;
  float* wtv   = wtk + 27*HD_;

  k_cast     <<<CAST_BLOCKS + 31, 256, 0, stream>>>(x, xb, qkv_w, wqkvb, proj_w, wprojb,
                                                    pqw, pkw, pvw, wtq, wtk, wtv);
  k_qkv      <<<dim3(BN_/64, 9),  256, 0, stream>>>(xb, wqkvb, raw_q, raw_k, raw_v);
  k_pool_slab<<<3*784,            256, 0, stream>>>(raw_q, raw_k, raw_v,
                                                    wtq, wtk, wtv,
                                                    nqw, nqb, nkw, nkb, nvw, nvb,
                                                    rph, rpw, rpt,
                                                    qp, Qaug, Kt, Vtt);
  k_attn     <<<BH_*98,           512, 0, stream>>>(Qaug, Kt, Vtt, qp, attb);
  k_proj     <<<dim3(BN_/64, 3),  256, 0, stream>>>(attb, wprojb, proj_b, (float*)d_out);
}

// Round 10
// 194.944 us; speedup vs baseline: 1.0017x; 1.0008x over previous
//
#include <hip/hip_runtime.h>

// Problem constants (fixed by reference)
#define B_    2
#define NH_   4
#define T_    8
#define H_    14
#define W_    14
#define HW_   196             // H*W
#define HD_   96
#define DIM_  384
#define N_    1568            // T*H*W
#define BH_   (B_*NH_)        // 8
#define BN_   (B_*N_)         // 3136
#define BHN_  (BH_*N_)        // 12544
#define CAUG_ 160             // 96 + 36 one-hot/bias + 28 pad

typedef unsigned short bf_t;
typedef unsigned int   u32;
typedef __attribute__((ext_vector_type(8))) short bf16x8;
typedef __attribute__((ext_vector_type(4))) float f32x4;

#define LOG2E 1.4426950408889634f
#define QSCALE_LOG2E 0.14724445f   /* 96^-0.5 * log2(e) */

static __device__ __forceinline__ float lo16(u32 v){ union{u32 i; float f;}x; x.i = v<<16;           return x.f; }
static __device__ __forceinline__ float hi16(u32 v){ union{u32 i; float f;}x; x.i = v & 0xffff0000u; return x.f; }
static __device__ __forceinline__ float b2f(bf_t v){ union{u32 i; float f;}x; x.i = ((u32)v)<<16;    return x.f; }
static __device__ __forceinline__ bf_t  f2b(float f){
  union{float f; u32 i;} x; x.f = f;
  return (bf_t)((x.i + 0x7fffu + ((x.i>>16)&1u)) >> 16);   // RNE
}
static __device__ __forceinline__ u32 pack2(float a, float b){
  return (u32)f2b(a) | ((u32)f2b(b) << 16);
}
// fragment-tile index for a row-major [R][384] matrix element (row, k)
static __device__ __forceinline__ size_t ftidx(int row, int k){
  return ((((size_t)(row>>4))*12 + (k>>5))*64 + ((k>>3)&3)*16 + (row&15))*8 + (k&7);
}

// ---------------------------------------------------------------------------
// K0: cast x / qkv_w / proj_w fp32 -> bf16 in FRAGMENT-TILED layout, plus
// conv-weight transpose [96][27]->[27][96] fp32 (last 31 blocks).
// ---------------------------------------------------------------------------
#define NA_ (BN_*DIM_)        // 1,204,224
#define NB_ (3*DIM_*DIM_)     //   442,368
#define NC_ (DIM_*DIM_)       //   147,456
#define CAST_BLOCKS ((NA_+NB_+NC_)/4/256)   // 1752 exactly

__global__ __launch_bounds__(256) void k_cast(
    const float* __restrict__ a, bf_t* __restrict__ ad,
    const float* __restrict__ b, bf_t* __restrict__ bd,
    const float* __restrict__ c, bf_t* __restrict__ cd,
    const float* __restrict__ wq, const float* __restrict__ wk,
    const float* __restrict__ wv, float* __restrict__ tq,
    float* __restrict__ tk, float* __restrict__ tv){
  if (blockIdx.x < CAST_BLOCKS){
    const int i = blockIdx.x*256 + threadIdx.x;     // float4 index
    const int i4 = i*4;
    float4 v; bf_t* dst; int row, k;
    if (i4 < NA_){
      v = ((const float4*)a)[i];
      dst = ad; row = i4/DIM_; k = i4%DIM_;
    } else if (i4 < NA_+NB_){
      const int f = i4 - NA_;
      v = ((const float4*)b)[i - NA_/4];
      dst = bd; row = f/DIM_; k = f%DIM_;
    } else {
      const int f = i4 - NA_ - NB_;
      v = ((const float4*)c)[i - (NA_+NB_)/4];
      dst = cd; row = f/DIM_; k = f%DIM_;
    }
    ushort4 o; o.x = f2b(v.x); o.y = f2b(v.y); o.z = f2b(v.z); o.w = f2b(v.w);
    *(ushort4*)(dst + ftidx(row, k)) = o;           // k%4==0 -> 8B aligned
  } else {
    const int idx = (blockIdx.x - CAST_BLOCKS)*256 + threadIdx.x;
    if (idx >= 3*HD_*27) return;
    const int t = idx / (HD_*27), rem = idx % (HD_*27);
    const int ch = rem / 27, j = rem % 27;
    const float* s = (t==0)? wq : (t==1)? wk : wv;
    float* d       = (t==0)? tq : (t==1)? tk : tv;
    d[j*HD_ + ch] = s[ch*27 + j];
  }
}

// ---------------------------------------------------------------------------
// K1: QKV GEMM via MFMA, fragment-tiled operands.
// R21: LDS-staged epilogue. Old: 32 scalar 2B global stores/thread, each
// with a recomputed /384,/96 div-chain (~320 VALU). New: MFMA frags ->
// LDS tile [64][136] (pad kills quad-row bank alias), barrier, then each
// thread writes 4x uint4 coalesced (every 32-col segment lies in ONE
// head/s plane since gcd(128,96)=32).
// R22: unchanged resubmission (R21 run showed pool +7.5us on IDENTICAL
// pool code -> environmental noise; re-measuring to disambiguate).
// ---------------------------------------------------------------------------
__global__ __launch_bounds__(256) void k_qkv(const bf_t* __restrict__ Xt,
    const bf_t* __restrict__ Wt,
    bf_t* __restrict__ q, bf_t* __restrict__ k, bf_t* __restrict__ v){
  __shared__ __align__(16) bf_t tile[64][136];
  const int wid = threadIdx.x >> 6, lane = threadIdx.x & 63;
  const int wr = wid & 1, wc = wid >> 1;
  const int nl = lane & 15, quad = lane >> 4;
  const int r0 = blockIdx.x*64 + wr*32;
  const int mt0 = r0 >> 4;
  const int nt0 = blockIdx.y*8 + wc*4;
  f32x4 acc[2][4];
  #pragma unroll
  for (int i = 0; i < 2; ++i)
    #pragma unroll
    for (int j = 0; j < 4; ++j) acc[i][j] = (f32x4){0.f,0.f,0.f,0.f};
  const bf_t* A0 = Xt + ((size_t)mt0*12*64 + lane)*8;
  const bf_t* B0 = Wt + ((size_t)nt0*12*64 + lane)*8;
  #pragma unroll 2
  for (int k0 = 0; k0 < 12; ++k0){
    const bf16x8 a0 = *(const bf16x8*)(A0 + k0*512);
    const bf16x8 a1 = *(const bf16x8*)(A0 + 12*512 + k0*512);
    bf16x8 bf[4];
    #pragma unroll
    for (int j = 0; j < 4; ++j) bf[j] = *(const bf16x8*)(B0 + (size_t)(j*12 + k0)*512);
    #pragma unroll
    for (int j = 0; j < 4; ++j){
      acc[0][j] = __builtin_amdgcn_mfma_f32_16x16x32_bf16(a0, bf[j], acc[0][j], 0, 0, 0);
      acc[1][j] = __builtin_amdgcn_mfma_f32_16x16x32_bf16(a1, bf[j], acc[1][j], 0, 0, 0);
    }
  }
  // frags -> LDS tile (local row = wr*32+i*16+quad*4+r, local col = wc*64+j*16+nl)
  #pragma unroll
  for (int i = 0; i < 2; ++i)
    #pragma unroll
    for (int r = 0; r < 4; ++r){
      const int lrow = wr*32 + i*16 + quad*4 + r;
      #pragma unroll
      for (int j = 0; j < 4; ++j)
        tile[lrow][wc*64 + j*16 + nl] = f2b(acc[i][j][r]);
    }
  __syncthreads();
  // coalesced store: thread t -> row t>>2, 32-col segment (t&3)*32
  {
    const int row = threadIdx.x >> 2, seg = threadIdx.x & 3;
    const int m  = blockIdx.x*64 + row;
    const int bb = m / N_, nn = m % N_;
    const int cg0 = blockIdx.y*128 + seg*32;      // global col of segment start
    const int s    = cg0 / DIM_;
    const int remS = cg0 - s*DIM_;
    const int head = remS / HD_, hc0 = remS % HD_;   // segment fits one plane
    bf_t* dst = ((s==0) ? q : (s==1) ? k : v)
              + ((size_t)(bb*NH_ + head)*N_ + nn)*HD_ + hc0;
    #pragma unroll
    for (int kk = 0; kk < 4; ++kk)
      *(uint4*)(dst + kk*8) = *(const uint4*)&tile[row][seg*32 + kk*8];
  }
}

static __device__ __forceinline__ void ln_butterfly(
    float v0, float v1, float& mean, float& rstd){
  float s  = v0 + v1;
  float s2 = v0*v0 + v1*v1;
  #pragma unroll
  for (int off = 32; off > 0; off >>= 1){
    s  += __shfl_xor(s,  off);
    s2 += __shfl_xor(s2, off);
  }
  mean = s * (1.f/HD_);
  const float var = fmaxf(s2*(1.f/HD_) - mean*mean, 0.f);
  rstd = rsqrtf(var + 1e-6f);
}

// ---------------------------------------------------------------------------
// K2: LDS-slab pooled conv+LN, 16 tokens/block (4 waves x 4 tokens).
// Halo slab 162 rows (3t x 3h x 18w) x 96ch bf16 = 31.1 KB.
// R19 decode retained: bh = blockIdx.x & 7 (XCD-pinned; FETCH 22.2->3.9 MB
// verified). Compute structure = R16 (proven best at ~48 us).
// ---------------------------------------------------------------------------
union PoolSM {
  bf_t  slab[162][HD_];       // 31,104 B  (phase 1)
  float qtmp[4][4][HD_];      //  6,144 B  (phase 2, sec 0; per-wave)
  u32   vres[16][48];         //  3,072 B  (phase 2, sec 2)
};

__global__ __launch_bounds__(256) void k_pool_slab(
    const bf_t* __restrict__ qr_, const bf_t* __restrict__ kr_, const bf_t* __restrict__ vr_,
    const float* __restrict__ wtq, const float* __restrict__ wtk, const float* __restrict__ wtv,
    const float* __restrict__ gq, const float* __restrict__ bq,
    const float* __restrict__ gk, const float* __restrict__ bk,
    const float* __restrict__ gv, const float* __restrict__ bv,
    const float* __restrict__ rph, const float* __restrict__ rpw,
    const float* __restrict__ rpt,
    bf_t* __restrict__ qp, bf_t* __restrict__ Qaug,
    bf_t* __restrict__ Kt, bf_t* __restrict__ Vtt){
  __shared__ __align__(16) PoolSM sm;
  const int wid = threadIdx.x >> 6, lane = threadIdx.x & 63;
  const int bh   = blockIdx.x & 7;          // XCD-pinned (2352 = 8 x 294)
  const int rest = blockIdx.x >> 3;
  const int sec  = rest / 98;
  const int tok0 = (rest % 98)*16;
  const bf_t*  src = (sec==0)? qr_ : (sec==1)? kr_ : vr_;
  const float* wt  = (sec==0)? wtq : (sec==1)? wtk : wtv;
  const float* g   = (sec==0)? gq  : (sec==1)? gk  : gv;
  const float* be  = (sec==0)? bq  : (sec==1)? bk  : bv;
  const bf_t* base = src + (size_t)bh*N_*HD_;

  // per-lane channel pair; first weight trio + LN params overlap staging
  const int c0 = (lane < 48) ? 2*lane : 0;
  float2 wcur[3], wnxt[3];
  #pragma unroll
  for (int dw = 0; dw < 3; ++dw) wcur[dw] = *(const float2*)(wt + dw*HD_ + c0);
  const float gg0 = g[c0], gg1 = g[c0+1], be0 = be[c0], be1 = be[c0+1];

  // ---- staging: batched loads into regs, then LDS writes (vmcnt pipeline) --
  {
    uint4 stg[8];
    #pragma unroll
    for (int it = 0; it < 8; ++it){
      const int li = threadIdx.x + it*256;
      const int lc = (li < 162*12) ? li : (162*12 - 1);
      const int rw = lc / 12, ss = lc % 12;
      const int aa = rw/54, bb2 = (rw%54)/18, cc = rw%18;
      int nn = tok0 + (aa-1)*HW_ + (bb2-1)*W_ + (cc-1);
      nn = min(max(nn, 0), N_-1);
      stg[it] = *(const uint4*)(base + (size_t)nn*HD_ + ss*8);
    }
    #pragma unroll
    for (int it = 0; it < 8; ++it){
      const int li = threadIdx.x + it*256;
      if (li < 162*12){
        const int rw = li / 12, ss = li % 12;
        *(uint4*)&sm.slab[rw][ss*8] = stg[it];
      }
    }
  }
  __syncthreads();

  // token coordinates (wave-uniform) + 27-bit validity masks
  int tt[4], hh[4], ww[4];
  u32 mr[4];
  #pragma unroll
  for (int tk = 0; tk < 4; ++tk){
    const int n = tok0 + wid*4 + tk;
    tt[tk] = n / HW_;
    const int rm = n % HW_;
    hh[tk] = rm / W_; ww[tk] = rm % W_;
    const u32 wb = (ww[tk] > 0 ? 1u : 0u) | 2u | (ww[tk] < W_-1 ? 4u : 0u);
    const u32 h9 = (hh[tk] > 0 ? wb : 0u) | (wb << 3) | (hh[tk] < H_-1 ? (wb << 6) : 0u);
    mr[tk] = (tt[tk] > 0 ? h9 : 0u) | (h9 << 9) | (tt[tk] < T_-1 ? (h9 << 18) : 0u);
  }

  // ---- phase 1: conv, software-pipelined row reads ----
  float v0[4] = {0.f,0.f,0.f,0.f}, v1[4] = {0.f,0.f,0.f,0.f};
  u32 rr[6], rrn[6];
  #pragma unroll
  for (int s = 0; s < 6; ++s) rr[s] = *(const u32*)&sm.slab[wid*4 + s][c0];
  #pragma unroll 1
  for (int j9 = 0; j9 < 9; ++j9){
    if (j9 < 8){
      const int jn = j9 + 1;
      const int rbn = (jn/3)*54 + (jn%3)*18 + wid*4;
      #pragma unroll
      for (int s = 0; s < 6; ++s) rrn[s] = *(const u32*)&sm.slab[rbn + s][c0];
      #pragma unroll
      for (int dw = 0; dw < 3; ++dw)
        wnxt[dw] = *(const float2*)(wt + (jn*3 + dw)*HD_ + c0);
    }
    #pragma unroll
    for (int tk = 0; tk < 4; ++tk){
      #pragma unroll
      for (int dw = 0; dw < 3; ++dw){
        const u32 d = (mr[tk] & (1u << dw)) ? rr[tk+dw] : 0u;
        v0[tk] = fmaf(wcur[dw].x, lo16(d), v0[tk]);
        v1[tk] = fmaf(wcur[dw].y, hi16(d), v1[tk]);
      }
      mr[tk] >>= 3;
    }
    #pragma unroll
    for (int s = 0; s < 6; ++s) rr[s] = rrn[s];
    #pragma unroll
    for (int dw = 0; dw < 3; ++dw) wcur[dw] = wnxt[dw];
  }
  // LayerNorm per token (results stay in v0/v1)
  #pragma unroll
  for (int tk = 0; tk < 4; ++tk){
    float a = v0[tk], b = v1[tk];
    if (lane >= 48){ a = 0.f; b = 0.f; }
    float mean, rstd;
    ln_butterfly(a, b, mean, rstd);
    v0[tk] = (a - mean)*rstd*gg0 + be0;
    v1[tk] = (b - mean)*rstd*gg1 + be1;
  }

  // ---- phase 2: outputs (qtmp/vres overlay slab; barrier before overlay) --
  if (sec == 0){
    __syncthreads();                              // slab -> qtmp overlay
    #pragma unroll
    for (int tk = 0; tk < 4; ++tk){
      const int n = tok0 + wid*4 + tk;
      const int token = bh*N_ + n;
      if (lane < 48){
        ((u32*)qp)  [(size_t)token*48 + lane] = pack2(v0[tk], v1[tk]);
        ((u32*)Qaug)[(size_t)token*80 + lane] = pack2(v0[tk]*QSCALE_LOG2E, v1[tk]*QSCALE_LOG2E);
        *(float2*)&sm.qtmp[wid][tk][c0] = make_float2(v0[tk], v1[tk]);
      }
    }
    // qtmp written/read by the SAME wave -> ordered by lgkmcnt, no barrier
    #pragma unroll
    for (int tk = 0; tk < 4; ++tk){
      const int n = tok0 + wid*4 + tk;
      const int token = bh*N_ + n;
      if (lane < 36){
        const float* tb; int idx;
        if (lane < 14)      { tb = rph; idx = hh[tk] - lane      + 13; }
        else if (lane < 28) { tb = rpw; idx = ww[tk] - (lane-14) + 13; }
        else                { tb = rpt; idx = tt[tk] - (lane-28) +  7; }
        const float4* t4 = (const float4*)(tb + (size_t)idx*HD_);
        const float4* q4 = (const float4*)&sm.qtmp[wid][tk][0];
        float ap[4] = {0.f, 0.f, 0.f, 0.f};
        #pragma unroll
        for (int i = 0; i < 24; ++i){
          const float4 rv = t4[i];
          const float4 qv = q4[i];                 // ds_read_b128 broadcast
          ap[i & 3] = fmaf(qv.x, rv.x,
                      fmaf(qv.y, rv.y,
                      fmaf(qv.z, rv.z,
                      fmaf(qv.w, rv.w, ap[i & 3]))));
        }
        const float acc = (ap[0] + ap[1]) + (ap[2] + ap[3]);
        Qaug[(size_t)token*CAUG_ + HD_ + lane] = f2b(acc * LOG2E);
      } else {
        Qaug[(size_t)token*CAUG_ + HD_ + lane] = 0;
      }
    }
  } else if (sec == 1){
    // no LDS use in this branch -> no barrier needed
    #pragma unroll
    for (int tk = 0; tk < 4; ++tk){
      const int n = tok0 + wid*4 + tk;
      const int tl = n >> 4, nr = n & 15;
      if (lane < 48){
        const size_t idx = ((((size_t)bh*98 + tl)*5 + (lane>>4))*64
                           + ((lane&15)>>2)*16 + nr)*4 + (lane&3);
        ((u32*)Kt)[idx] = pack2(v0[tk], v1[tk]);
      } else {
        const int m = lane - 48;
        u32 pr_[2];
        #pragma unroll
        for (int h2 = 0; h2 < 2; ++h2){
          u32 w_ = 0;
          #pragma unroll
          for (int e = 0; e < 2; ++e){
            const int jj = 4*m + 2*h2 + e;
            bool on = (jj < 14) ? (jj == hh[tk]) : (jj < 28) ? (jj-14 == ww[tk])
                     : (jj < 36) ? (jj-28 == tt[tk]) : false;
            if (on) w_ |= (0x3F80u << (16*e));
          }
          pr_[h2] = w_;
        }
        const size_t bidx = ((((size_t)bh*98 + tl)*5 + (3 + (m>>3)))*64
                            + ((m&7)>>1)*16 + nr)*4 + 2*(m&1);
        *(uint2*)((u32*)Kt + bidx) = make_uint2(pr_[0], pr_[1]);
      }
    }
  } else {
    __syncthreads();                              // slab -> vres overlay
    #pragma unroll
    for (int tk = 0; tk < 4; ++tk){
      if (lane < 48) sm.vres[wid*4 + tk][lane] = pack2(v0[tk], v1[tk]);
    }
    __syncthreads();
    if (threadIdx.x < 2*HD_){
      const int grp = threadIdx.x / HD_, c = threadIdx.x % HD_;
      const int t0g = grp*8;
      u32 o[4];
      #pragma unroll
      for (int i = 0; i < 4; ++i){
        const u32 a = sm.vres[t0g + 2*i][c>>1], b = sm.vres[t0g + 2*i+1][c>>1];
        const u32 ra = (c&1) ? (a >> 16) : (a & 0xffffu);
        const u32 rb = (c&1) ? (b >> 16) : (b & 0xffffu);
        o[i] = ra | (rb << 16);
      }
      const int n0g = tok0 + t0g;
      const int pr = n0g >> 5, qd = (n0g & 31) >> 3;
      bf_t* dst = Vtt + ((((size_t)bh*49 + pr)*6 + (c>>4))*64 + qd*16 + (c&15))*8;
      *(uint4*)dst = make_uint4(o[0], o[1], o[2], o[3]);
    }
  }
}

// ---------------------------------------------------------------------------
// K4: MFMA flash attention, 8-wave in-block split-K, fragment-tiled K/V
// (R19 proven form; R20's 2-q-tile variant halved occupancy and regressed).
// bh = blockIdx.x & 7 pins each (batch,head)'s 98 q-tile blocks to one XCD.
// ---------------------------------------------------------------------------
__global__ __launch_bounds__(512) void k_attn(
    const bf_t* __restrict__ Qaug, const bf_t* __restrict__ Kt,
    const bf_t* __restrict__ Vtt, const bf_t* __restrict__ qp,
    bf_t* __restrict__ attb){
  __shared__ __align__(16) short Pb[8][16][40];   // per-wave P tile (+8 pad)
  __shared__ bf_t Os[8][16][96];                  // per-wave partial O (bf16)
  __shared__ float ms[8][16], ls[8][16];          // per-wave partial m, l
  const int wid = threadIdx.x >> 6, lane = threadIdx.x & 63;
  const int bh = blockIdx.x & 7, qt = blockIdx.x >> 3;   // XCD-aware (784=8x98)
  const int q0 = qt*16;
  const int nl = lane & 15, quad = lane >> 4;

  bf16x8 qa[5];
  {
    const bf_t* Qrow = Qaug + ((size_t)bh*N_ + q0 + nl)*CAUG_ + quad*8;
    #pragma unroll
    for (int i = 0; i < 5; ++i) qa[i] = *(const bf16x8*)(Qrow + i*32);
  }
  short* Pw = &Pb[wid][0][0];

  f32x4 O[6];
  #pragma unroll
  for (int i = 0; i < 6; ++i) O[i] = (f32x4){0.f,0.f,0.f,0.f};
  float mc[4]   = {0.f,0.f,0.f,0.f};
  float rmax[4] = {-3e38f,-3e38f,-3e38f,-3e38f};
  float l[4]    = {0.f,0.f,0.f,0.f};

  auto s_tile = [&](int tl, int half){
    const bf_t* Kp = Kt + (((size_t)bh*98 + tl)*5*64 + lane)*8;
    f32x4 s = (f32x4){0.f,0.f,0.f,0.f};
    #pragma unroll
    for (int i = 0; i < 5; ++i)
      s = __builtin_amdgcn_mfma_f32_16x16x32_bf16(qa[i], *(const bf16x8*)(Kp + i*512), s, 0, 0, 0);
    #pragma unroll
    for (int r = 0; r < 4; ++r){
      rmax[r] = fmaxf(rmax[r], s[r]);
      const float p = exp2f(s[r] - mc[r]);
      l[r] += p;
      Pw[(quad*4 + r)*40 + half*16 + nl] = (short)f2b(p);
    }
  };
  auto rescale = [&](){
    #pragma unroll
    for (int r = 0; r < 4; ++r){
      float tm = rmax[r];
      tm = fmaxf(tm, __shfl_xor(tm, 1));
      tm = fmaxf(tm, __shfl_xor(tm, 2));
      tm = fmaxf(tm, __shfl_xor(tm, 4));
      tm = fmaxf(tm, __shfl_xor(tm, 8));
      const float mn = fmaxf(mc[r], tm);
      const float al = exp2f(mc[r] - mn);
      mc[r] = mn; l[r] *= al;
      #pragma unroll
      for (int ct = 0; ct < 6; ++ct) O[ct][r] *= al;
    }
  };

  const int p0 = (wid == 0) ? 0 : (7 + 6*(wid-1));
  const int npairs = (wid == 0) ? 7 : 6;
  #pragma unroll 1
  for (int pi = 0; pi < npairs; ++pi){
    const int kp = p0 + pi;
    s_tile(2*kp,     0);
    s_tile(2*kp + 1, 1);
    const bf16x8 pa = *(const bf16x8*)(Pw + nl*40 + quad*8);
    const bf_t* Vp = Vtt + (((size_t)bh*49 + kp)*6*64 + lane)*8;
    #pragma unroll
    for (int ct = 0; ct < 6; ++ct)
      O[ct] = __builtin_amdgcn_mfma_f32_16x16x32_bf16(pa, *(const bf16x8*)(Vp + ct*512), O[ct], 0, 0, 0);
    if (pi == npairs-1) rescale();
  }

  #pragma unroll
  for (int r = 0; r < 4; ++r){
    float ls_ = l[r];
    ls_ += __shfl_xor(ls_, 1); ls_ += __shfl_xor(ls_, 2);
    ls_ += __shfl_xor(ls_, 4); ls_ += __shfl_xor(ls_, 8);
    if (nl == 0){ ms[wid][quad*4 + r] = mc[r]; ls[wid][quad*4 + r] = ls_; }
    #pragma unroll
    for (int ct = 0; ct < 6; ++ct) Os[wid][quad*4 + r][ct*16 + nl] = f2b(O[ct][r]);
  }
  __syncthreads();

  const int bb = bh >> 2, head = bh & 3;
  const int grow0 = bb*N_ + q0;                   // multiple of 16
  for (int e = threadIdx.x; e < 16*96; e += 512){
    const int row = e / 96, col = e % 96;
    float mx = -3e38f;
    #pragma unroll
    for (int w = 0; w < 8; ++w) mx = fmaxf(mx, ms[w][row]);
    float L = 0.f, A = 0.f;
    #pragma unroll
    for (int w = 0; w < 8; ++w){
      const float wt = exp2f(ms[w][row] - mx);
      L += wt*ls[w][row];
      A += wt*b2f(Os[w][row][col]);
    }
    const float val = A/L + b2f(qp[((size_t)bh*N_ + q0 + row)*HD_ + col]);
    attb[ftidx(grow0 + row, head*HD_ + col)] = f2b(val);
  }
}

// ---------------------------------------------------------------------------
// K5: output projection via MFMA, fragment-tiled A (attb) and B (Wpt).
// ---------------------------------------------------------------------------
__global__ __launch_bounds__(256) void k_proj(const bf_t* __restrict__ At,
    const bf_t* __restrict__ Wpt, const float* __restrict__ pb,
    float* __restrict__ out){
  const int wid = threadIdx.x >> 6, lane = threadIdx.x & 63;
  const int wr = wid & 1, wc = wid >> 1;
  const int nl = lane & 15, quad = lane >> 4;
  const int r0 = blockIdx.x*64 + wr*32;
  const int mt0 = r0 >> 4;
  const int nt0 = blockIdx.y*8 + wc*4;
  f32x4 acc[2][4];
  #pragma unroll
  for (int i = 0; i < 2; ++i)
    #pragma unroll
    for (int j = 0; j < 4; ++j) acc[i][j] = (f32x4){0.f,0.f,0.f,0.f};
  const bf_t* A0 = At  + ((size_t)mt0*12*64 + lane)*8;
  const bf_t* B0 = Wpt + ((size_t)nt0*12*64 + lane)*8;
  #pragma unroll 2
  for (int k0 = 0; k0 < 12; ++k0){
    const bf16x8 a0 = *(const bf16x8*)(A0 + k0*512);
    const bf16x8 a1 = *(const bf16x8*)(A0 + 12*512 + k0*512);
    bf16x8 bf[4];
    #pragma unroll
    for (int j = 0; j < 4; ++j) bf[j] = *(const bf16x8*)(B0 + (size_t)(j*12 + k0)*512);
    #pragma unroll
    for (int j = 0; j < 4; ++j){
      acc[0][j] = __builtin_amdgcn_mfma_f32_16x16x32_bf16(a0, bf[j], acc[0][j], 0, 0, 0);
      acc[1][j] = __builtin_amdgcn_mfma_f32_16x16x32_bf16(a1, bf[j], acc[1][j], 0, 0, 0);
    }
  }
  #pragma unroll
  for (int i = 0; i < 2; ++i){
    #pragma unroll
    for (int r = 0; r < 4; ++r){
      const int m = r0 + i*16 + quad*4 + r;
      #pragma unroll
      for (int j = 0; j < 4; ++j){
        const int col = (nt0 + j)*16 + nl;
        out[(size_t)m*DIM_ + col] = acc[i][j][r] + pb[col];
      }
    }
  }
}

// ---------------------------------------------------------------------------
extern "C" void kernel_launch(void* const* d_in, const int* in_sizes, int n_in,
                              void* d_out, int out_size, void* d_ws, size_t ws_size,
                              hipStream_t stream){
  const float* x      = (const float*)d_in[0];
  const float* qkv_w  = (const float*)d_in[1];
  const float* proj_w = (const float*)d_in[2];
  const float* proj_b = (const float*)d_in[3];
  const float* pqw    = (const float*)d_in[4];
  const float* pkw    = (const float*)d_in[5];
  const float* pvw    = (const float*)d_in[6];
  const float* nqw    = (const float*)d_in[7];
  const float* nqb    = (const float*)d_in[8];
  const float* nkw    = (const float*)d_in[9];
  const float* nkb    = (const float*)d_in[10];
  const float* nvw    = (const float*)d_in[11];
  const float* nvb    = (const float*)d_in[12];
  const float* rph    = (const float*)d_in[13];
  const float* rpw    = (const float*)d_in[14];
  const float* rpt    = (const float*)d_in[15];

  // Workspace (bytes), ~23.7 MB total. attb overlays raw_q after pooling.
  char* p = (char*)d_ws;
  const size_t RAW = (size_t)BH_*N_*HD_*2;       // 2,408,448 B
  const size_t AUG = (size_t)BH_*N_*CAUG_*2;     // 4,014,080 B
  bf_t* xb     = (bf_t*)(p);                     // frag-tiled
  bf_t* wqkvb  = (bf_t*)(p + RAW);               // frag-tiled
  bf_t* wprojb = (bf_t*)(p + RAW + 884736);      // frag-tiled
  char* p2 = p + RAW + 884736 + 294912;
  bf_t* raw_q  = (bf_t*)(p2);
  bf_t* raw_k  = (bf_t*)(p2 + RAW);
  bf_t* raw_v  = (bf_t*)(p2 + 2*RAW);
  bf_t* attb   = raw_q;                          // overlays raw_q (frag-tiled)
  bf_t* qp     = (bf_t*)(p2 + 3*RAW);
  bf_t* Qaug   = (bf_t*)(p2 + 4*RAW);
  bf_t* Kt     = (bf_t*)(p2 + 4*RAW + AUG);      // tiled Kaug
  bf_t* Vtt    = (bf_t*)(p2 + 4*RAW + 2*AUG);    // tiled V
  float* wtq   = (float*)(p2 + 4*RAW + 2*AUG + RAW);   // 3 x 27x96 fp32
  float* wtk   = wtq + 27*HD_;
  float* wtv   = wtk + 27*HD_;

  k_cast     <<<CAST_BLOCKS + 31, 256, 0, stream>>>(x, xb, qkv_w, wqkvb, proj_w, wprojb,
                                                    pqw, pkw, pvw, wtq, wtk, wtv);
  k_qkv      <<<dim3(BN_/64, 9),  256, 0, stream>>>(xb, wqkvb, raw_q, raw_k, raw_v);
  k_pool_slab<<<3*784,            256, 0, stream>>>(raw_q, raw_k, raw_v,
                                                    wtq, wtk, wtv,
                                                    nqw, nqb, nkw, nkb, nvw, nvb,
                                                    rph, rpw, rpt,
                                                    qp, Qaug, Kt, Vtt);
  k_attn     <<<BH_*98,           512, 0, stream>>>(Qaug, Kt, Vtt, qp, attb);
  k_proj     <<<dim3(BN_/64, 3),  256, 0, stream>>>(attb, wprojb, proj_b, (float*)d_out);
}

// Round 11
// 192.672 us; speedup vs baseline: 1.0136x; 1.0118x over previous
//
#include <hip/hip_runtime.h>

// Problem constants (fixed by reference)
#define B_    2
#define NH_   4
#define T_    8
#define H_    14
#define W_    14
#define HW_   196             // H*W
#define HD_   96
#define DIM_  384
#define N_    1568            // T*H*W
#define BH_   (B_*NH_)        // 8
#define BN_   (B_*N_)         // 3136
#define BHN_  (BH_*N_)        // 12544
#define CAUG_ 160             // 96 + 36 one-hot/bias + 28 pad

typedef unsigned short bf_t;
typedef unsigned int   u32;
typedef __attribute__((ext_vector_type(8))) short bf16x8;
typedef __attribute__((ext_vector_type(4))) float f32x4;

#define LOG2E 1.4426950408889634f
#define QSCALE_LOG2E 0.14724445f   /* 96^-0.5 * log2(e) */

static __device__ __forceinline__ float lo16(u32 v){ union{u32 i; float f;}x; x.i = v<<16;           return x.f; }
static __device__ __forceinline__ float hi16(u32 v){ union{u32 i; float f;}x; x.i = v & 0xffff0000u; return x.f; }
static __device__ __forceinline__ float b2f(bf_t v){ union{u32 i; float f;}x; x.i = ((u32)v)<<16;    return x.f; }
static __device__ __forceinline__ bf_t  f2b(float f){
  union{float f; u32 i;} x; x.f = f;
  return (bf_t)((x.i + 0x7fffu + ((x.i>>16)&1u)) >> 16);   // RNE
}
static __device__ __forceinline__ u32 pack2(float a, float b){
  return (u32)f2b(a) | ((u32)f2b(b) << 16);
}
// fragment-tile index for a row-major [R][384] matrix element (row, k)
static __device__ __forceinline__ size_t ftidx(int row, int k){
  return ((((size_t)(row>>4))*12 + (k>>5))*64 + ((k>>3)&3)*16 + (row&15))*8 + (k&7);
}

// ---------------------------------------------------------------------------
// K0: cast x / qkv_w / proj_w fp32 -> bf16 in FRAGMENT-TILED layout, plus
// conv-weight transpose [96][27]->[27][96] fp32 (last 31 blocks).
// ---------------------------------------------------------------------------
#define NA_ (BN_*DIM_)        // 1,204,224
#define NB_ (3*DIM_*DIM_)     //   442,368
#define NC_ (DIM_*DIM_)       //   147,456
#define CAST_BLOCKS ((NA_+NB_+NC_)/4/256)   // 1752 exactly

__global__ __launch_bounds__(256) void k_cast(
    const float* __restrict__ a, bf_t* __restrict__ ad,
    const float* __restrict__ b, bf_t* __restrict__ bd,
    const float* __restrict__ c, bf_t* __restrict__ cd,
    const float* __restrict__ wq, const float* __restrict__ wk,
    const float* __restrict__ wv, float* __restrict__ tq,
    float* __restrict__ tk, float* __restrict__ tv){
  if (blockIdx.x < CAST_BLOCKS){
    const int i = blockIdx.x*256 + threadIdx.x;     // float4 index
    const int i4 = i*4;
    float4 v; bf_t* dst; int row, k;
    if (i4 < NA_){
      v = ((const float4*)a)[i];
      dst = ad; row = i4/DIM_; k = i4%DIM_;
    } else if (i4 < NA_+NB_){
      const int f = i4 - NA_;
      v = ((const float4*)b)[i - NA_/4];
      dst = bd; row = f/DIM_; k = f%DIM_;
    } else {
      const int f = i4 - NA_ - NB_;
      v = ((const float4*)c)[i - (NA_+NB_)/4];
      dst = cd; row = f/DIM_; k = f%DIM_;
    }
    ushort4 o; o.x = f2b(v.x); o.y = f2b(v.y); o.z = f2b(v.z); o.w = f2b(v.w);
    *(ushort4*)(dst + ftidx(row, k)) = o;           // k%4==0 -> 8B aligned
  } else {
    const int idx = (blockIdx.x - CAST_BLOCKS)*256 + threadIdx.x;
    if (idx >= 3*HD_*27) return;
    const int t = idx / (HD_*27), rem = idx % (HD_*27);
    const int ch = rem / 27, j = rem % 27;
    const float* s = (t==0)? wq : (t==1)? wk : wv;
    float* d       = (t==0)? tq : (t==1)? tk : tv;
    d[j*HD_ + ch] = s[ch*27 + j];
  }
}

// ---------------------------------------------------------------------------
// K1: QKV GEMM via MFMA, fragment-tiled operands.
// R23: scalar-store epilogue RESTORED (R21/R22's LDS-staged epilogue
// measured +1.5us with pool constant -- the scalar stores were already
// hidden under wave-level overlap).
// ---------------------------------------------------------------------------
__global__ __launch_bounds__(256) void k_qkv(const bf_t* __restrict__ Xt,
    const bf_t* __restrict__ Wt,
    bf_t* __restrict__ q, bf_t* __restrict__ k, bf_t* __restrict__ v){
  const int wid = threadIdx.x >> 6, lane = threadIdx.x & 63;
  const int wr = wid & 1, wc = wid >> 1;
  const int nl = lane & 15, quad = lane >> 4;
  const int r0 = blockIdx.x*64 + wr*32;
  const int mt0 = r0 >> 4;
  const int nt0 = blockIdx.y*8 + wc*4;
  f32x4 acc[2][4];
  #pragma unroll
  for (int i = 0; i < 2; ++i)
    #pragma unroll
    for (int j = 0; j < 4; ++j) acc[i][j] = (f32x4){0.f,0.f,0.f,0.f};
  const bf_t* A0 = Xt + ((size_t)mt0*12*64 + lane)*8;
  const bf_t* B0 = Wt + ((size_t)nt0*12*64 + lane)*8;
  #pragma unroll 2
  for (int k0 = 0; k0 < 12; ++k0){
    const bf16x8 a0 = *(const bf16x8*)(A0 + k0*512);
    const bf16x8 a1 = *(const bf16x8*)(A0 + 12*512 + k0*512);
    bf16x8 bf[4];
    #pragma unroll
    for (int j = 0; j < 4; ++j) bf[j] = *(const bf16x8*)(B0 + (size_t)(j*12 + k0)*512);
    #pragma unroll
    for (int j = 0; j < 4; ++j){
      acc[0][j] = __builtin_amdgcn_mfma_f32_16x16x32_bf16(a0, bf[j], acc[0][j], 0, 0, 0);
      acc[1][j] = __builtin_amdgcn_mfma_f32_16x16x32_bf16(a1, bf[j], acc[1][j], 0, 0, 0);
    }
  }
  #pragma unroll
  for (int i = 0; i < 2; ++i){
    #pragma unroll
    for (int r = 0; r < 4; ++r){
      const int m  = r0 + i*16 + quad*4 + r;
      const int bb = m / N_, nn = m % N_;
      #pragma unroll
      for (int j = 0; j < 4; ++j){
        const int col = (nt0 + j)*16 + nl;
        const int s = col / DIM_, rem = col - s*DIM_;
        const int head = rem / HD_, hc = rem % HD_;
        bf_t* dst = (s==0) ? q : (s==1) ? k : v;
        dst[((size_t)(bb*NH_ + head)*N_ + nn)*HD_ + hc] = f2b(acc[i][j][r]);
      }
    }
  }
}

static __device__ __forceinline__ void ln_butterfly(
    float v0, float v1, float& mean, float& rstd){
  float s  = v0 + v1;
  float s2 = v0*v0 + v1*v1;
  #pragma unroll
  for (int off = 32; off > 0; off >>= 1){
    s  += __shfl_xor(s,  off);
    s2 += __shfl_xor(s2, off);
  }
  mean = s * (1.f/HD_);
  const float var = fmaxf(s2*(1.f/HD_) - mean*mean, 0.f);
  rstd = rsqrtf(var + 1e-6f);
}

// ---------------------------------------------------------------------------
// K2: LDS-slab pooled conv+LN, 16 tokens/block (4 waves x 4 tokens).
// Halo slab 162 rows (3t x 3h x 18w) x 96ch bf16 = 31.1 KB.
// R23 = exact R16 form (best measured: total 192.38, pool 49.8).
// Session ledger: R14 forced-occupancy spill (-), R17 deep pipeline (-),
// R19 XCD pinning (FETCH 22->3.9MB but timing-neutral, +0.7 total).
// ---------------------------------------------------------------------------
union PoolSM {
  bf_t  slab[162][HD_];       // 31,104 B  (phase 1)
  float qtmp[4][4][HD_];      //  6,144 B  (phase 2, sec 0; per-wave)
  u32   vres[16][48];         //  3,072 B  (phase 2, sec 2)
};

__global__ __launch_bounds__(256) void k_pool_slab(
    const bf_t* __restrict__ qr_, const bf_t* __restrict__ kr_, const bf_t* __restrict__ vr_,
    const float* __restrict__ wtq, const float* __restrict__ wtk, const float* __restrict__ wtv,
    const float* __restrict__ gq, const float* __restrict__ bq,
    const float* __restrict__ gk, const float* __restrict__ bk,
    const float* __restrict__ gv, const float* __restrict__ bv,
    const float* __restrict__ rph, const float* __restrict__ rpw,
    const float* __restrict__ rpt,
    bf_t* __restrict__ qp, bf_t* __restrict__ Qaug,
    bf_t* __restrict__ Kt, bf_t* __restrict__ Vtt){
  __shared__ __align__(16) PoolSM sm;
  const int wid = threadIdx.x >> 6, lane = threadIdx.x & 63;
  const int sec = blockIdx.x / 784;
  const int rr_ = blockIdx.x % 784;
  const int bh = rr_ / 98, tok0 = (rr_ % 98)*16;
  const bf_t*  src = (sec==0)? qr_ : (sec==1)? kr_ : vr_;
  const float* wt  = (sec==0)? wtq : (sec==1)? wtk : wtv;
  const float* g   = (sec==0)? gq  : (sec==1)? gk  : gv;
  const float* be  = (sec==0)? bq  : (sec==1)? bk  : bv;
  const bf_t* base = src + (size_t)bh*N_*HD_;

  // per-lane channel pair; first weight trio + LN params overlap staging
  const int c0 = (lane < 48) ? 2*lane : 0;
  float2 wcur[3], wnxt[3];
  #pragma unroll
  for (int dw = 0; dw < 3; ++dw) wcur[dw] = *(const float2*)(wt + dw*HD_ + c0);
  const float gg0 = g[c0], gg1 = g[c0+1], be0 = be[c0], be1 = be[c0+1];

  // ---- staging: batched loads into regs, then LDS writes (vmcnt pipeline) --
  {
    uint4 stg[8];
    #pragma unroll
    for (int it = 0; it < 8; ++it){
      const int li = threadIdx.x + it*256;
      const int lc = (li < 162*12) ? li : (162*12 - 1);
      const int rw = lc / 12, ss = lc % 12;
      const int aa = rw/54, bb2 = (rw%54)/18, cc = rw%18;
      int nn = tok0 + (aa-1)*HW_ + (bb2-1)*W_ + (cc-1);
      nn = min(max(nn, 0), N_-1);
      stg[it] = *(const uint4*)(base + (size_t)nn*HD_ + ss*8);
    }
    #pragma unroll
    for (int it = 0; it < 8; ++it){
      const int li = threadIdx.x + it*256;
      if (li < 162*12){
        const int rw = li / 12, ss = li % 12;
        *(uint4*)&sm.slab[rw][ss*8] = stg[it];
      }
    }
  }
  __syncthreads();

  // token coordinates (wave-uniform) + 27-bit validity masks
  int tt[4], hh[4], ww[4];
  u32 mr[4];
  #pragma unroll
  for (int tk = 0; tk < 4; ++tk){
    const int n = tok0 + wid*4 + tk;
    tt[tk] = n / HW_;
    const int rm = n % HW_;
    hh[tk] = rm / W_; ww[tk] = rm % W_;
    const u32 wb = (ww[tk] > 0 ? 1u : 0u) | 2u | (ww[tk] < W_-1 ? 4u : 0u);
    const u32 h9 = (hh[tk] > 0 ? wb : 0u) | (wb << 3) | (hh[tk] < H_-1 ? (wb << 6) : 0u);
    mr[tk] = (tt[tk] > 0 ? h9 : 0u) | (h9 << 9) | (tt[tk] < T_-1 ? (h9 << 18) : 0u);
  }

  // ---- phase 1: conv, software-pipelined row reads ----
  float v0[4] = {0.f,0.f,0.f,0.f}, v1[4] = {0.f,0.f,0.f,0.f};
  u32 rr[6], rrn[6];
  #pragma unroll
  for (int s = 0; s < 6; ++s) rr[s] = *(const u32*)&sm.slab[wid*4 + s][c0];
  #pragma unroll 1
  for (int j9 = 0; j9 < 9; ++j9){
    if (j9 < 8){
      const int jn = j9 + 1;
      const int rbn = (jn/3)*54 + (jn%3)*18 + wid*4;
      #pragma unroll
      for (int s = 0; s < 6; ++s) rrn[s] = *(const u32*)&sm.slab[rbn + s][c0];
      #pragma unroll
      for (int dw = 0; dw < 3; ++dw)
        wnxt[dw] = *(const float2*)(wt + (jn*3 + dw)*HD_ + c0);
    }
    #pragma unroll
    for (int tk = 0; tk < 4; ++tk){
      #pragma unroll
      for (int dw = 0; dw < 3; ++dw){
        const u32 d = (mr[tk] & (1u << dw)) ? rr[tk+dw] : 0u;
        v0[tk] = fmaf(wcur[dw].x, lo16(d), v0[tk]);
        v1[tk] = fmaf(wcur[dw].y, hi16(d), v1[tk]);
      }
      mr[tk] >>= 3;
    }
    #pragma unroll
    for (int s = 0; s < 6; ++s) rr[s] = rrn[s];
    #pragma unroll
    for (int dw = 0; dw < 3; ++dw) wcur[dw] = wnxt[dw];
  }
  // LayerNorm per token (results stay in v0/v1)
  #pragma unroll
  for (int tk = 0; tk < 4; ++tk){
    float a = v0[tk], b = v1[tk];
    if (lane >= 48){ a = 0.f; b = 0.f; }
    float mean, rstd;
    ln_butterfly(a, b, mean, rstd);
    v0[tk] = (a - mean)*rstd*gg0 + be0;
    v1[tk] = (b - mean)*rstd*gg1 + be1;
  }

  // ---- phase 2: outputs (qtmp/vres overlay slab; barrier before overlay) --
  if (sec == 0){
    __syncthreads();                              // slab -> qtmp overlay
    #pragma unroll
    for (int tk = 0; tk < 4; ++tk){
      const int n = tok0 + wid*4 + tk;
      const int token = bh*N_ + n;
      if (lane < 48){
        ((u32*)qp)  [(size_t)token*48 + lane] = pack2(v0[tk], v1[tk]);
        ((u32*)Qaug)[(size_t)token*80 + lane] = pack2(v0[tk]*QSCALE_LOG2E, v1[tk]*QSCALE_LOG2E);
        *(float2*)&sm.qtmp[wid][tk][c0] = make_float2(v0[tk], v1[tk]);
      }
    }
    // qtmp written/read by the SAME wave -> ordered by lgkmcnt, no barrier
    #pragma unroll
    for (int tk = 0; tk < 4; ++tk){
      const int n = tok0 + wid*4 + tk;
      const int token = bh*N_ + n;
      if (lane < 36){
        const float* tb; int idx;
        if (lane < 14)      { tb = rph; idx = hh[tk] - lane      + 13; }
        else if (lane < 28) { tb = rpw; idx = ww[tk] - (lane-14) + 13; }
        else                { tb = rpt; idx = tt[tk] - (lane-28) +  7; }
        const float4* t4 = (const float4*)(tb + (size_t)idx*HD_);
        const float4* q4 = (const float4*)&sm.qtmp[wid][tk][0];
        float ap[4] = {0.f, 0.f, 0.f, 0.f};
        #pragma unroll
        for (int i = 0; i < 24; ++i){
          const float4 rv = t4[i];
          const float4 qv = q4[i];                 // ds_read_b128 broadcast
          ap[i & 3] = fmaf(qv.x, rv.x,
                      fmaf(qv.y, rv.y,
                      fmaf(qv.z, rv.z,
                      fmaf(qv.w, rv.w, ap[i & 3]))));
        }
        const float acc = (ap[0] + ap[1]) + (ap[2] + ap[3]);
        Qaug[(size_t)token*CAUG_ + HD_ + lane] = f2b(acc * LOG2E);
      } else {
        Qaug[(size_t)token*CAUG_ + HD_ + lane] = 0;
      }
    }
  } else if (sec == 1){
    // no LDS use in this branch -> no barrier needed
    #pragma unroll
    for (int tk = 0; tk < 4; ++tk){
      const int n = tok0 + wid*4 + tk;
      const int tl = n >> 4, nr = n & 15;
      if (lane < 48){
        const size_t idx = ((((size_t)bh*98 + tl)*5 + (lane>>4))*64
                           + ((lane&15)>>2)*16 + nr)*4 + (lane&3);
        ((u32*)Kt)[idx] = pack2(v0[tk], v1[tk]);
      } else {
        const int m = lane - 48;
        u32 pr_[2];
        #pragma unroll
        for (int h2 = 0; h2 < 2; ++h2){
          u32 w_ = 0;
          #pragma unroll
          for (int e = 0; e < 2; ++e){
            const int jj = 4*m + 2*h2 + e;
            bool on = (jj < 14) ? (jj == hh[tk]) : (jj < 28) ? (jj-14 == ww[tk])
                     : (jj < 36) ? (jj-28 == tt[tk]) : false;
            if (on) w_ |= (0x3F80u << (16*e));
          }
          pr_[h2] = w_;
        }
        const size_t bidx = ((((size_t)bh*98 + tl)*5 + (3 + (m>>3)))*64
                            + ((m&7)>>1)*16 + nr)*4 + 2*(m&1);
        *(uint2*)((u32*)Kt + bidx) = make_uint2(pr_[0], pr_[1]);
      }
    }
  } else {
    __syncthreads();                              // slab -> vres overlay
    #pragma unroll
    for (int tk = 0; tk < 4; ++tk){
      if (lane < 48) sm.vres[wid*4 + tk][lane] = pack2(v0[tk], v1[tk]);
    }
    __syncthreads();
    if (threadIdx.x < 2*HD_){
      const int grp = threadIdx.x / HD_, c = threadIdx.x % HD_;
      const int t0g = grp*8;
      u32 o[4];
      #pragma unroll
      for (int i = 0; i < 4; ++i){
        const u32 a = sm.vres[t0g + 2*i][c>>1], b = sm.vres[t0g + 2*i+1][c>>1];
        const u32 ra = (c&1) ? (a >> 16) : (a & 0xffffu);
        const u32 rb = (c&1) ? (b >> 16) : (b & 0xffffu);
        o[i] = ra | (rb << 16);
      }
      const int n0g = tok0 + t0g;
      const int pr = n0g >> 5, qd = (n0g & 31) >> 3;
      bf_t* dst = Vtt + ((((size_t)bh*49 + pr)*6 + (c>>4))*64 + qd*16 + (c&15))*8;
      *(uint4*)dst = make_uint4(o[0], o[1], o[2], o[3]);
    }
  }
}

// ---------------------------------------------------------------------------
// K4: MFMA flash attention, 8-wave in-block split-K, fragment-tiled K/V.
// Os partials stored BF16 (LDS 60.4 -> 35.8 KB => 4 blocks/CU, 2x waves).
// R23: bh = blockIdx.x / 98 (R16 form; the &7 swizzle measured neutral).
// ---------------------------------------------------------------------------
__global__ __launch_bounds__(512) void k_attn(
    const bf_t* __restrict__ Qaug, const bf_t* __restrict__ Kt,
    const bf_t* __restrict__ Vtt, const bf_t* __restrict__ qp,
    bf_t* __restrict__ attb){
  __shared__ __align__(16) short Pb[8][16][40];   // per-wave P tile (+8 pad)
  __shared__ bf_t Os[8][16][96];                  // per-wave partial O (bf16)
  __shared__ float ms[8][16], ls[8][16];          // per-wave partial m, l
  const int wid = threadIdx.x >> 6, lane = threadIdx.x & 63;
  const int bh = blockIdx.x / 98, qt = blockIdx.x % 98;
  const int q0 = qt*16;
  const int nl = lane & 15, quad = lane >> 4;

  bf16x8 qa[5];
  {
    const bf_t* Qrow = Qaug + ((size_t)bh*N_ + q0 + nl)*CAUG_ + quad*8;
    #pragma unroll
    for (int i = 0; i < 5; ++i) qa[i] = *(const bf16x8*)(Qrow + i*32);
  }
  short* Pw = &Pb[wid][0][0];

  f32x4 O[6];
  #pragma unroll
  for (int i = 0; i < 6; ++i) O[i] = (f32x4){0.f,0.f,0.f,0.f};
  float mc[4]   = {0.f,0.f,0.f,0.f};
  float rmax[4] = {-3e38f,-3e38f,-3e38f,-3e38f};
  float l[4]    = {0.f,0.f,0.f,0.f};

  auto s_tile = [&](int tl, int half){
    const bf_t* Kp = Kt + (((size_t)bh*98 + tl)*5*64 + lane)*8;
    f32x4 s = (f32x4){0.f,0.f,0.f,0.f};
    #pragma unroll
    for (int i = 0; i < 5; ++i)
      s = __builtin_amdgcn_mfma_f32_16x16x32_bf16(qa[i], *(const bf16x8*)(Kp + i*512), s, 0, 0, 0);
    #pragma unroll
    for (int r = 0; r < 4; ++r){
      rmax[r] = fmaxf(rmax[r], s[r]);
      const float p = exp2f(s[r] - mc[r]);
      l[r] += p;
      Pw[(quad*4 + r)*40 + half*16 + nl] = (short)f2b(p);
    }
  };
  auto rescale = [&](){
    #pragma unroll
    for (int r = 0; r < 4; ++r){
      float tm = rmax[r];
      tm = fmaxf(tm, __shfl_xor(tm, 1));
      tm = fmaxf(tm, __shfl_xor(tm, 2));
      tm = fmaxf(tm, __shfl_xor(tm, 4));
      tm = fmaxf(tm, __shfl_xor(tm, 8));
      const float mn = fmaxf(mc[r], tm);
      const float al = exp2f(mc[r] - mn);
      mc[r] = mn; l[r] *= al;
      #pragma unroll
      for (int ct = 0; ct < 6; ++ct) O[ct][r] *= al;
    }
  };

  const int p0 = (wid == 0) ? 0 : (7 + 6*(wid-1));
  const int npairs = (wid == 0) ? 7 : 6;
  #pragma unroll 1
  for (int pi = 0; pi < npairs; ++pi){
    const int kp = p0 + pi;
    s_tile(2*kp,     0);
    s_tile(2*kp + 1, 1);
    const bf16x8 pa = *(const bf16x8*)(Pw + nl*40 + quad*8);
    const bf_t* Vp = Vtt + (((size_t)bh*49 + kp)*6*64 + lane)*8;
    #pragma unroll
    for (int ct = 0; ct < 6; ++ct)
      O[ct] = __builtin_amdgcn_mfma_f32_16x16x32_bf16(pa, *(const bf16x8*)(Vp + ct*512), O[ct], 0, 0, 0);
    if (pi == npairs-1) rescale();
  }

  #pragma unroll
  for (int r = 0; r < 4; ++r){
    float ls_ = l[r];
    ls_ += __shfl_xor(ls_, 1); ls_ += __shfl_xor(ls_, 2);
    ls_ += __shfl_xor(ls_, 4); ls_ += __shfl_xor(ls_, 8);
    if (nl == 0){ ms[wid][quad*4 + r] = mc[r]; ls[wid][quad*4 + r] = ls_; }
    #pragma unroll
    for (int ct = 0; ct < 6; ++ct) Os[wid][quad*4 + r][ct*16 + nl] = f2b(O[ct][r]);
  }
  __syncthreads();

  const int bb = bh >> 2, head = bh & 3;
  const int grow0 = bb*N_ + q0;                   // multiple of 16
  for (int e = threadIdx.x; e < 16*96; e += 512){
    const int row = e / 96, col = e % 96;
    float mx = -3e38f;
    #pragma unroll
    for (int w = 0; w < 8; ++w) mx = fmaxf(mx, ms[w][row]);
    float L = 0.f, A = 0.f;
    #pragma unroll
    for (int w = 0; w < 8; ++w){
      const float wt = exp2f(ms[w][row] - mx);
      L += wt*ls[w][row];
      A += wt*b2f(Os[w][row][col]);
    }
    const float val = A/L + b2f(qp[((size_t)bh*N_ + q0 + row)*HD_ + col]);
    attb[ftidx(grow0 + row, head*HD_ + col)] = f2b(val);
  }
}

// ---------------------------------------------------------------------------
// K5: output projection via MFMA, fragment-tiled A (attb) and B (Wpt).
// ---------------------------------------------------------------------------
__global__ __launch_bounds__(256) void k_proj(const bf_t* __restrict__ At,
    const bf_t* __restrict__ Wpt, const float* __restrict__ pb,
    float* __restrict__ out){
  const int wid = threadIdx.x >> 6, lane = threadIdx.x & 63;
  const int wr = wid & 1, wc = wid >> 1;
  const int nl = lane & 15, quad = lane >> 4;
  const int r0 = blockIdx.x*64 + wr*32;
  const int mt0 = r0 >> 4;
  const int nt0 = blockIdx.y*8 + wc*4;
  f32x4 acc[2][4];
  #pragma unroll
  for (int i = 0; i < 2; ++i)
    #pragma unroll
    for (int j = 0; j < 4; ++j) acc[i][j] = (f32x4){0.f,0.f,0.f,0.f};
  const bf_t* A0 = At  + ((size_t)mt0*12*64 + lane)*8;
  const bf_t* B0 = Wpt + ((size_t)nt0*12*64 + lane)*8;
  #pragma unroll 2
  for (int k0 = 0; k0 < 12; ++k0){
    const bf16x8 a0 = *(const bf16x8*)(A0 + k0*512);
    const bf16x8 a1 = *(const bf16x8*)(A0 + 12*512 + k0*512);
    bf16x8 bf[4];
    #pragma unroll
    for (int j = 0; j < 4; ++j) bf[j] = *(const bf16x8*)(B0 + (size_t)(j*12 + k0)*512);
    #pragma unroll
    for (int j = 0; j < 4; ++j){
      acc[0][j] = __builtin_amdgcn_mfma_f32_16x16x32_bf16(a0, bf[j], acc[0][j], 0, 0, 0);
      acc[1][j] = __builtin_amdgcn_mfma_f32_16x16x32_bf16(a1, bf[j], acc[1][j], 0, 0, 0);
    }
  }
  #pragma unroll
  for (int i = 0; i < 2; ++i){
    #pragma unroll
    for (int r = 0; r < 4; ++r){
      const int m = r0 + i*16 + quad*4 + r;
      #pragma unroll
      for (int j = 0; j < 4; ++j){
        const int col = (nt0 + j)*16 + nl;
        out[(size_t)m*DIM_ + col] = acc[i][j][r] + pb[col];
      }
    }
  }
}

// ---------------------------------------------------------------------------
extern "C" void kernel_launch(void* const* d_in, const int* in_sizes, int n_in,
                              void* d_out, int out_size, void* d_ws, size_t ws_size,
                              hipStream_t stream){
  const float* x      = (const float*)d_in[0];
  const float* qkv_w  = (const float*)d_in[1];
  const float* proj_w = (const float*)d_in[2];
  const float* proj_b = (const float*)d_in[3];
  const float* pqw    = (const float*)d_in[4];
  const float* pkw    = (const float*)d_in[5];
  const float* pvw    = (const float*)d_in[6];
  const float* nqw    = (const float*)d_in[7];
  const float* nqb    = (const float*)d_in[8];
  const float* nkw    = (const float*)d_in[9];
  const float* nkb    = (const float*)d_in[10];
  const float* nvw    = (const float*)d_in[11];
  const float* nvb    = (const float*)d_in[12];
  const float* rph    = (const float*)d_in[13];
  const float* rpw    = (const float*)d_in[14];
  const float* rpt    = (const float*)d_in[15];

  // Workspace (bytes), ~23.7 MB total. attb overlays raw_q after pooling.
  char* p = (char*)d_ws;
  const size_t RAW = (size_t)BH_*N_*HD_*2;       // 2,408,448 B
  const size_t AUG = (size_t)BH_*N_*CAUG_*2;     // 4,014,080 B
  bf_t* xb     = (bf_t*)(p);                     // frag-tiled
  bf_t* wqkvb  = (bf_t*)(p + RAW);               // frag-tiled
  bf_t* wprojb = (bf_t*)(p + RAW + 884736);      // frag-tiled
  char* p2 = p + RAW + 884736 + 294912;
  bf_t* raw_q  = (bf_t*)(p2);
  bf_t* raw_k  = (bf_t*)(p2 + RAW);
  bf_t* raw_v  = (bf_t*)(p2 + 2*RAW);
  bf_t* attb   = raw_q;                          // overlays raw_q (frag-tiled)
  bf_t* qp     = (bf_t*)(p2 + 3*RAW);
  bf_t* Qaug   = (bf_t*)(p2 + 4*RAW);
  bf_t* Kt     = (bf_t*)(p2 + 4*RAW + AUG);      // tiled Kaug
  bf_t* Vtt    = (bf_t*)(p2 + 4*RAW + 2*AUG);    // tiled V
  float* wtq   = (float*)(p2 + 4*RAW + 2*AUG + RAW);   // 3 x 27x96 fp32
  float* wtk   = wtq + 27*HD_;
  float* wtv   = wtk + 27*HD_;

  k_cast     <<<CAST_BLOCKS + 31, 256, 0, stream>>>(x, xb, qkv_w, wqkvb, proj_w, wprojb,
                                                    pqw, pkw, pvw, wtq, wtk, wtv);
  k_qkv      <<<dim3(BN_/64, 9),  256, 0, stream>>>(xb, wqkvb, raw_q, raw_k, raw_v);
  k_pool_slab<<<3*784,            256, 0, stream>>>(raw_q, raw_k, raw_v,
                                                    wtq, wtk, wtv,
                                                    nqw, nqb, nkw, nkb, nvw, nvb,
                                                    rph, rpw, rpt,
                                                    qp, Qaug, Kt, Vtt);
  k_attn     <<<BH_*98,           512, 0, stream>>>(Qaug, Kt, Vtt, qp, attb);
  k_proj     <<<dim3(BN_/64, 3),  256, 0, stream>>>(attb, wprojb, proj_b, (float*)d_out);
}

// Round 12
// 189.856 us; speedup vs baseline: 1.0286x; 1.0148x over previous
//
#include <hip/hip_runtime.h>

// Problem constants (fixed by reference)
#define B_    2
#define NH_   4
#define T_    8
#define H_    14
#define W_    14
#define HW_   196             // H*W
#define HD_   96
#define DIM_  384
#define N_    1568            // T*H*W
#define BH_   (B_*NH_)        // 8
#define BN_   (B_*N_)         // 3136
#define BHN_  (BH_*N_)        // 12544
#define CAUG_ 160             // 96 + 36 one-hot/bias + 28 pad

typedef unsigned short bf_t;
typedef unsigned int   u32;
typedef __attribute__((ext_vector_type(8))) short bf16x8;
typedef __attribute__((ext_vector_type(4))) float f32x4;

#define LOG2E 1.4426950408889634f
#define QSCALE_LOG2E 0.14724445f   /* 96^-0.5 * log2(e) */

static __device__ __forceinline__ float lo16(u32 v){ union{u32 i; float f;}x; x.i = v<<16;           return x.f; }
static __device__ __forceinline__ float hi16(u32 v){ union{u32 i; float f;}x; x.i = v & 0xffff0000u; return x.f; }
static __device__ __forceinline__ float b2f(bf_t v){ union{u32 i; float f;}x; x.i = ((u32)v)<<16;    return x.f; }
static __device__ __forceinline__ bf_t  f2b(float f){
  union{float f; u32 i;} x; x.f = f;
  return (bf_t)((x.i + 0x7fffu + ((x.i>>16)&1u)) >> 16);   // RNE
}
static __device__ __forceinline__ u32 pack2(float a, float b){
  return (u32)f2b(a) | ((u32)f2b(b) << 16);
}
// fragment-tile index for a row-major [R][384] matrix element (row, k)
static __device__ __forceinline__ size_t ftidx(int row, int k){
  return ((((size_t)(row>>4))*12 + (k>>5))*64 + ((k>>3)&3)*16 + (row&15))*8 + (k&7);
}

// ---------------------------------------------------------------------------
// K0: cast x / qkv_w / proj_w fp32 -> bf16 in FRAGMENT-TILED layout, plus
// conv-weight transpose [96][27]->[27][96] fp32 (last 31 blocks).
// R24: TILE-PER-WAVE rewrite of the matrix part. Old: 1 ushort4 (8B) store
// per thread through ftidx -> consecutive threads write 16B chunks at 256B
// stride (each 64B line gets 16B, ~4x write amplification). New: one wave
// owns one 16x32 fragment tile; within a tile ftidx(row,k) = base + l*8 + s
// for l=(q<<4)|r, so lane l writes 16B contiguous and the wave writes a
// fully-coalesced 1KB tile. Reads: 2x float4/lane, 128B/row contiguous.
// 3504 tiles / 4 waves = 876 blocks (+31 conv-w blocks unchanged).
// ---------------------------------------------------------------------------
#define NA_ (BN_*DIM_)        // 1,204,224
#define NB_ (3*DIM_*DIM_)     //   442,368
#define NC_ (DIM_*DIM_)       //   147,456
#define TILES_X 2352          // (3136/16)*(384/32)
#define TILES_B 864           // (1152/16)*12
#define TILES_C 288           // (384/16)*12
#define CAST_MBLOCKS ((TILES_X+TILES_B+TILES_C)/4)   // 876 exactly

__global__ __launch_bounds__(256) void k_cast(
    const float* __restrict__ a, bf_t* __restrict__ ad,
    const float* __restrict__ b, bf_t* __restrict__ bd,
    const float* __restrict__ c, bf_t* __restrict__ cd,
    const float* __restrict__ wq, const float* __restrict__ wk,
    const float* __restrict__ wv, float* __restrict__ tq,
    float* __restrict__ tk, float* __restrict__ tv){
  if (blockIdx.x < CAST_MBLOCKS){
    const int tile = blockIdx.x*4 + (threadIdx.x >> 6);
    const int lane = threadIdx.x & 63;
    const float* src; bf_t* dst; int tl;
    if (tile < TILES_X)                { src = a; dst = ad; tl = tile; }
    else if (tile < TILES_X + TILES_B) { src = b; dst = bd; tl = tile - TILES_X; }
    else                               { src = c; dst = cd; tl = tile - TILES_X - TILES_B; }
    const int mt = tl / 12, kt = tl % 12;
    const int row = mt*16 + (lane & 15);
    const int k0  = kt*32 + (lane >> 4)*8;
    const float4 v0 = *(const float4*)(src + (size_t)row*DIM_ + k0);
    const float4 v1 = *(const float4*)(src + (size_t)row*DIM_ + k0 + 4);
    const u32 w0 = pack2(v0.x, v0.y), w1 = pack2(v0.z, v0.w);
    const u32 w2 = pack2(v1.x, v1.y), w3 = pack2(v1.z, v1.w);
    // within-tile: ftidx = tilebase + ((k>>3)&3)*128 + (row&15)*8 + (k&7)
    //            = tilebase + lane*8 + s  for lane = (q<<4)|r
    *(uint4*)(dst + (size_t)tl*512 + lane*8) = make_uint4(w0, w1, w2, w3);
  } else {
    const int idx = (blockIdx.x - CAST_MBLOCKS)*256 + threadIdx.x;
    if (idx >= 3*HD_*27) return;
    const int t = idx / (HD_*27), rem = idx % (HD_*27);
    const int ch = rem / 27, j = rem % 27;
    const float* s = (t==0)? wq : (t==1)? wk : wv;
    float* d       = (t==0)? tq : (t==1)? tk : tv;
    d[j*HD_ + ch] = s[ch*27 + j];
  }
}

// ---------------------------------------------------------------------------
// K1: QKV GEMM via MFMA, fragment-tiled operands.
// R23: scalar-store epilogue (R21/R22's LDS-staged epilogue measured +1.5us
// with pool constant -- scalar stores were already hidden under overlap).
// ---------------------------------------------------------------------------
__global__ __launch_bounds__(256) void k_qkv(const bf_t* __restrict__ Xt,
    const bf_t* __restrict__ Wt,
    bf_t* __restrict__ q, bf_t* __restrict__ k, bf_t* __restrict__ v){
  const int wid = threadIdx.x >> 6, lane = threadIdx.x & 63;
  const int wr = wid & 1, wc = wid >> 1;
  const int nl = lane & 15, quad = lane >> 4;
  const int r0 = blockIdx.x*64 + wr*32;
  const int mt0 = r0 >> 4;
  const int nt0 = blockIdx.y*8 + wc*4;
  f32x4 acc[2][4];
  #pragma unroll
  for (int i = 0; i < 2; ++i)
    #pragma unroll
    for (int j = 0; j < 4; ++j) acc[i][j] = (f32x4){0.f,0.f,0.f,0.f};
  const bf_t* A0 = Xt + ((size_t)mt0*12*64 + lane)*8;
  const bf_t* B0 = Wt + ((size_t)nt0*12*64 + lane)*8;
  #pragma unroll 2
  for (int k0 = 0; k0 < 12; ++k0){
    const bf16x8 a0 = *(const bf16x8*)(A0 + k0*512);
    const bf16x8 a1 = *(const bf16x8*)(A0 + 12*512 + k0*512);
    bf16x8 bf[4];
    #pragma unroll
    for (int j = 0; j < 4; ++j) bf[j] = *(const bf16x8*)(B0 + (size_t)(j*12 + k0)*512);
    #pragma unroll
    for (int j = 0; j < 4; ++j){
      acc[0][j] = __builtin_amdgcn_mfma_f32_16x16x32_bf16(a0, bf[j], acc[0][j], 0, 0, 0);
      acc[1][j] = __builtin_amdgcn_mfma_f32_16x16x32_bf16(a1, bf[j], acc[1][j], 0, 0, 0);
    }
  }
  #pragma unroll
  for (int i = 0; i < 2; ++i){
    #pragma unroll
    for (int r = 0; r < 4; ++r){
      const int m  = r0 + i*16 + quad*4 + r;
      const int bb = m / N_, nn = m % N_;
      #pragma unroll
      for (int j = 0; j < 4; ++j){
        const int col = (nt0 + j)*16 + nl;
        const int s = col / DIM_, rem = col - s*DIM_;
        const int head = rem / HD_, hc = rem % HD_;
        bf_t* dst = (s==0) ? q : (s==1) ? k : v;
        dst[((size_t)(bb*NH_ + head)*N_ + nn)*HD_ + hc] = f2b(acc[i][j][r]);
      }
    }
  }
}

static __device__ __forceinline__ void ln_butterfly(
    float v0, float v1, float& mean, float& rstd){
  float s  = v0 + v1;
  float s2 = v0*v0 + v1*v1;
  #pragma unroll
  for (int off = 32; off > 0; off >>= 1){
    s  += __shfl_xor(s,  off);
    s2 += __shfl_xor(s2, off);
  }
  mean = s * (1.f/HD_);
  const float var = fmaxf(s2*(1.f/HD_) - mean*mean, 0.f);
  rstd = rsqrtf(var + 1e-6f);
}

// ---------------------------------------------------------------------------
// K2: LDS-slab pooled conv+LN, 16 tokens/block (4 waves x 4 tokens).
// Halo slab 162 rows (3t x 3h x 18w) x 96ch bf16 = 31.1 KB.
// R16 form (best measured). Ledger: R14 forced-occupancy spill (-),
// R17 deep pipeline (-), R19 XCD pinning (FETCH 22->3.9MB, timing-neutral).
// ---------------------------------------------------------------------------
union PoolSM {
  bf_t  slab[162][HD_];       // 31,104 B  (phase 1)
  float qtmp[4][4][HD_];      //  6,144 B  (phase 2, sec 0; per-wave)
  u32   vres[16][48];         //  3,072 B  (phase 2, sec 2)
};

__global__ __launch_bounds__(256) void k_pool_slab(
    const bf_t* __restrict__ qr_, const bf_t* __restrict__ kr_, const bf_t* __restrict__ vr_,
    const float* __restrict__ wtq, const float* __restrict__ wtk, const float* __restrict__ wtv,
    const float* __restrict__ gq, const float* __restrict__ bq,
    const float* __restrict__ gk, const float* __restrict__ bk,
    const float* __restrict__ gv, const float* __restrict__ bv,
    const float* __restrict__ rph, const float* __restrict__ rpw,
    const float* __restrict__ rpt,
    bf_t* __restrict__ qp, bf_t* __restrict__ Qaug,
    bf_t* __restrict__ Kt, bf_t* __restrict__ Vtt){
  __shared__ __align__(16) PoolSM sm;
  const int wid = threadIdx.x >> 6, lane = threadIdx.x & 63;
  const int sec = blockIdx.x / 784;
  const int rr_ = blockIdx.x % 784;
  const int bh = rr_ / 98, tok0 = (rr_ % 98)*16;
  const bf_t*  src = (sec==0)? qr_ : (sec==1)? kr_ : vr_;
  const float* wt  = (sec==0)? wtq : (sec==1)? wtk : wtv;
  const float* g   = (sec==0)? gq  : (sec==1)? gk  : gv;
  const float* be  = (sec==0)? bq  : (sec==1)? bk  : bv;
  const bf_t* base = src + (size_t)bh*N_*HD_;

  // per-lane channel pair; first weight trio + LN params overlap staging
  const int c0 = (lane < 48) ? 2*lane : 0;
  float2 wcur[3], wnxt[3];
  #pragma unroll
  for (int dw = 0; dw < 3; ++dw) wcur[dw] = *(const float2*)(wt + dw*HD_ + c0);
  const float gg0 = g[c0], gg1 = g[c0+1], be0 = be[c0], be1 = be[c0+1];

  // ---- staging: batched loads into regs, then LDS writes (vmcnt pipeline) --
  {
    uint4 stg[8];
    #pragma unroll
    for (int it = 0; it < 8; ++it){
      const int li = threadIdx.x + it*256;
      const int lc = (li < 162*12) ? li : (162*12 - 1);
      const int rw = lc / 12, ss = lc % 12;
      const int aa = rw/54, bb2 = (rw%54)/18, cc = rw%18;
      int nn = tok0 + (aa-1)*HW_ + (bb2-1)*W_ + (cc-1);
      nn = min(max(nn, 0), N_-1);
      stg[it] = *(const uint4*)(base + (size_t)nn*HD_ + ss*8);
    }
    #pragma unroll
    for (int it = 0; it < 8; ++it){
      const int li = threadIdx.x + it*256;
      if (li < 162*12){
        const int rw = li / 12, ss = li % 12;
        *(uint4*)&sm.slab[rw][ss*8] = stg[it];
      }
    }
  }
  __syncthreads();

  // token coordinates (wave-uniform) + 27-bit validity masks
  int tt[4], hh[4], ww[4];
  u32 mr[4];
  #pragma unroll
  for (int tk = 0; tk < 4; ++tk){
    const int n = tok0 + wid*4 + tk;
    tt[tk] = n / HW_;
    const int rm = n % HW_;
    hh[tk] = rm / W_; ww[tk] = rm % W_;
    const u32 wb = (ww[tk] > 0 ? 1u : 0u) | 2u | (ww[tk] < W_-1 ? 4u : 0u);
    const u32 h9 = (hh[tk] > 0 ? wb : 0u) | (wb << 3) | (hh[tk] < H_-1 ? (wb << 6) : 0u);
    mr[tk] = (tt[tk] > 0 ? h9 : 0u) | (h9 << 9) | (tt[tk] < T_-1 ? (h9 << 18) : 0u);
  }

  // ---- phase 1: conv, software-pipelined row reads ----
  float v0[4] = {0.f,0.f,0.f,0.f}, v1[4] = {0.f,0.f,0.f,0.f};
  u32 rr[6], rrn[6];
  #pragma unroll
  for (int s = 0; s < 6; ++s) rr[s] = *(const u32*)&sm.slab[wid*4 + s][c0];
  #pragma unroll 1
  for (int j9 = 0; j9 < 9; ++j9){
    if (j9 < 8){
      const int jn = j9 + 1;
      const int rbn = (jn/3)*54 + (jn%3)*18 + wid*4;
      #pragma unroll
      for (int s = 0; s < 6; ++s) rrn[s] = *(const u32*)&sm.slab[rbn + s][c0];
      #pragma unroll
      for (int dw = 0; dw < 3; ++dw)
        wnxt[dw] = *(const float2*)(wt + (jn*3 + dw)*HD_ + c0);
    }
    #pragma unroll
    for (int tk = 0; tk < 4; ++tk){
      #pragma unroll
      for (int dw = 0; dw < 3; ++dw){
        const u32 d = (mr[tk] & (1u << dw)) ? rr[tk+dw] : 0u;
        v0[tk] = fmaf(wcur[dw].x, lo16(d), v0[tk]);
        v1[tk] = fmaf(wcur[dw].y, hi16(d), v1[tk]);
      }
      mr[tk] >>= 3;
    }
    #pragma unroll
    for (int s = 0; s < 6; ++s) rr[s] = rrn[s];
    #pragma unroll
    for (int dw = 0; dw < 3; ++dw) wcur[dw] = wnxt[dw];
  }
  // LayerNorm per token (results stay in v0/v1)
  #pragma unroll
  for (int tk = 0; tk < 4; ++tk){
    float a = v0[tk], b = v1[tk];
    if (lane >= 48){ a = 0.f; b = 0.f; }
    float mean, rstd;
    ln_butterfly(a, b, mean, rstd);
    v0[tk] = (a - mean)*rstd*gg0 + be0;
    v1[tk] = (b - mean)*rstd*gg1 + be1;
  }

  // ---- phase 2: outputs (qtmp/vres overlay slab; barrier before overlay) --
  if (sec == 0){
    __syncthreads();                              // slab -> qtmp overlay
    #pragma unroll
    for (int tk = 0; tk < 4; ++tk){
      const int n = tok0 + wid*4 + tk;
      const int token = bh*N_ + n;
      if (lane < 48){
        ((u32*)qp)  [(size_t)token*48 + lane] = pack2(v0[tk], v1[tk]);
        ((u32*)Qaug)[(size_t)token*80 + lane] = pack2(v0[tk]*QSCALE_LOG2E, v1[tk]*QSCALE_LOG2E);
        *(float2*)&sm.qtmp[wid][tk][c0] = make_float2(v0[tk], v1[tk]);
      }
    }
    // qtmp written/read by the SAME wave -> ordered by lgkmcnt, no barrier
    #pragma unroll
    for (int tk = 0; tk < 4; ++tk){
      const int n = tok0 + wid*4 + tk;
      const int token = bh*N_ + n;
      if (lane < 36){
        const float* tb; int idx;
        if (lane < 14)      { tb = rph; idx = hh[tk] - lane      + 13; }
        else if (lane < 28) { tb = rpw; idx = ww[tk] - (lane-14) + 13; }
        else                { tb = rpt; idx = tt[tk] - (lane-28) +  7; }
        const float4* t4 = (const float4*)(tb + (size_t)idx*HD_);
        const float4* q4 = (const float4*)&sm.qtmp[wid][tk][0];
        float ap[4] = {0.f, 0.f, 0.f, 0.f};
        #pragma unroll
        for (int i = 0; i < 24; ++i){
          const float4 rv = t4[i];
          const float4 qv = q4[i];                 // ds_read_b128 broadcast
          ap[i & 3] = fmaf(qv.x, rv.x,
                      fmaf(qv.y, rv.y,
                      fmaf(qv.z, rv.z,
                      fmaf(qv.w, rv.w, ap[i & 3]))));
        }
        const float acc = (ap[0] + ap[1]) + (ap[2] + ap[3]);
        Qaug[(size_t)token*CAUG_ + HD_ + lane] = f2b(acc * LOG2E);
      } else {
        Qaug[(size_t)token*CAUG_ + HD_ + lane] = 0;
      }
    }
  } else if (sec == 1){
    // no LDS use in this branch -> no barrier needed
    #pragma unroll
    for (int tk = 0; tk < 4; ++tk){
      const int n = tok0 + wid*4 + tk;
      const int tl = n >> 4, nr = n & 15;
      if (lane < 48){
        const size_t idx = ((((size_t)bh*98 + tl)*5 + (lane>>4))*64
                           + ((lane&15)>>2)*16 + nr)*4 + (lane&3);
        ((u32*)Kt)[idx] = pack2(v0[tk], v1[tk]);
      } else {
        const int m = lane - 48;
        u32 pr_[2];
        #pragma unroll
        for (int h2 = 0; h2 < 2; ++h2){
          u32 w_ = 0;
          #pragma unroll
          for (int e = 0; e < 2; ++e){
            const int jj = 4*m + 2*h2 + e;
            bool on = (jj < 14) ? (jj == hh[tk]) : (jj < 28) ? (jj-14 == ww[tk])
                     : (jj < 36) ? (jj-28 == tt[tk]) : false;
            if (on) w_ |= (0x3F80u << (16*e));
          }
          pr_[h2] = w_;
        }
        const size_t bidx = ((((size_t)bh*98 + tl)*5 + (3 + (m>>3)))*64
                            + ((m&7)>>1)*16 + nr)*4 + 2*(m&1);
        *(uint2*)((u32*)Kt + bidx) = make_uint2(pr_[0], pr_[1]);
      }
    }
  } else {
    __syncthreads();                              // slab -> vres overlay
    #pragma unroll
    for (int tk = 0; tk < 4; ++tk){
      if (lane < 48) sm.vres[wid*4 + tk][lane] = pack2(v0[tk], v1[tk]);
    }
    __syncthreads();
    if (threadIdx.x < 2*HD_){
      const int grp = threadIdx.x / HD_, c = threadIdx.x % HD_;
      const int t0g = grp*8;
      u32 o[4];
      #pragma unroll
      for (int i = 0; i < 4; ++i){
        const u32 a = sm.vres[t0g + 2*i][c>>1], b = sm.vres[t0g + 2*i+1][c>>1];
        const u32 ra = (c&1) ? (a >> 16) : (a & 0xffffu);
        const u32 rb = (c&1) ? (b >> 16) : (b & 0xffffu);
        o[i] = ra | (rb << 16);
      }
      const int n0g = tok0 + t0g;
      const int pr = n0g >> 5, qd = (n0g & 31) >> 3;
      bf_t* dst = Vtt + ((((size_t)bh*49 + pr)*6 + (c>>4))*64 + qd*16 + (c&15))*8;
      *(uint4*)dst = make_uint4(o[0], o[1], o[2], o[3]);
    }
  }
}

// ---------------------------------------------------------------------------
// K4: MFMA flash attention, 8-wave in-block split-K, fragment-tiled K/V.
// Os partials stored BF16 (LDS 60.4 -> 35.8 KB => 4 blocks/CU, 2x waves).
// ---------------------------------------------------------------------------
__global__ __launch_bounds__(512) void k_attn(
    const bf_t* __restrict__ Qaug, const bf_t* __restrict__ Kt,
    const bf_t* __restrict__ Vtt, const bf_t* __restrict__ qp,
    bf_t* __restrict__ attb){
  __shared__ __align__(16) short Pb[8][16][40];   // per-wave P tile (+8 pad)
  __shared__ bf_t Os[8][16][96];                  // per-wave partial O (bf16)
  __shared__ float ms[8][16], ls[8][16];          // per-wave partial m, l
  const int wid = threadIdx.x >> 6, lane = threadIdx.x & 63;
  const int bh = blockIdx.x / 98, qt = blockIdx.x % 98;
  const int q0 = qt*16;
  const int nl = lane & 15, quad = lane >> 4;

  bf16x8 qa[5];
  {
    const bf_t* Qrow = Qaug + ((size_t)bh*N_ + q0 + nl)*CAUG_ + quad*8;
    #pragma unroll
    for (int i = 0; i < 5; ++i) qa[i] = *(const bf16x8*)(Qrow + i*32);
  }
  short* Pw = &Pb[wid][0][0];

  f32x4 O[6];
  #pragma unroll
  for (int i = 0; i < 6; ++i) O[i] = (f32x4){0.f,0.f,0.f,0.f};
  float mc[4]   = {0.f,0.f,0.f,0.f};
  float rmax[4] = {-3e38f,-3e38f,-3e38f,-3e38f};
  float l[4]    = {0.f,0.f,0.f,0.f};

  auto s_tile = [&](int tl, int half){
    const bf_t* Kp = Kt + (((size_t)bh*98 + tl)*5*64 + lane)*8;
    f32x4 s = (f32x4){0.f,0.f,0.f,0.f};
    #pragma unroll
    for (int i = 0; i < 5; ++i)
      s = __builtin_amdgcn_mfma_f32_16x16x32_bf16(qa[i], *(const bf16x8*)(Kp + i*512), s, 0, 0, 0);
    #pragma unroll
    for (int r = 0; r < 4; ++r){
      rmax[r] = fmaxf(rmax[r], s[r]);
      const float p = exp2f(s[r] - mc[r]);
      l[r] += p;
      Pw[(quad*4 + r)*40 + half*16 + nl] = (short)f2b(p);
    }
  };
  auto rescale = [&](){
    #pragma unroll
    for (int r = 0; r < 4; ++r){
      float tm = rmax[r];
      tm = fmaxf(tm, __shfl_xor(tm, 1));
      tm = fmaxf(tm, __shfl_xor(tm, 2));
      tm = fmaxf(tm, __shfl_xor(tm, 4));
      tm = fmaxf(tm, __shfl_xor(tm, 8));
      const float mn = fmaxf(mc[r], tm);
      const float al = exp2f(mc[r] - mn);
      mc[r] = mn; l[r] *= al;
      #pragma unroll
      for (int ct = 0; ct < 6; ++ct) O[ct][r] *= al;
    }
  };

  const int p0 = (wid == 0) ? 0 : (7 + 6*(wid-1));
  const int npairs = (wid == 0) ? 7 : 6;
  #pragma unroll 1
  for (int pi = 0; pi < npairs; ++pi){
    const int kp = p0 + pi;
    s_tile(2*kp,     0);
    s_tile(2*kp + 1, 1);
    const bf16x8 pa = *(const bf16x8*)(Pw + nl*40 + quad*8);
    const bf_t* Vp = Vtt + (((size_t)bh*49 + kp)*6*64 + lane)*8;
    #pragma unroll
    for (int ct = 0; ct < 6; ++ct)
      O[ct] = __builtin_amdgcn_mfma_f32_16x16x32_bf16(pa, *(const bf16x8*)(Vp + ct*512), O[ct], 0, 0, 0);
    if (pi == npairs-1) rescale();
  }

  #pragma unroll
  for (int r = 0; r < 4; ++r){
    float ls_ = l[r];
    ls_ += __shfl_xor(ls_, 1); ls_ += __shfl_xor(ls_, 2);
    ls_ += __shfl_xor(ls_, 4); ls_ += __shfl_xor(ls_, 8);
    if (nl == 0){ ms[wid][quad*4 + r] = mc[r]; ls[wid][quad*4 + r] = ls_; }
    #pragma unroll
    for (int ct = 0; ct < 6; ++ct) Os[wid][quad*4 + r][ct*16 + nl] = f2b(O[ct][r]);
  }
  __syncthreads();

  const int bb = bh >> 2, head = bh & 3;
  const int grow0 = bb*N_ + q0;                   // multiple of 16
  for (int e = threadIdx.x; e < 16*96; e += 512){
    const int row = e / 96, col = e % 96;
    float mx = -3e38f;
    #pragma unroll
    for (int w = 0; w < 8; ++w) mx = fmaxf(mx, ms[w][row]);
    float L = 0.f, A = 0.f;
    #pragma unroll
    for (int w = 0; w < 8; ++w){
      const float wt = exp2f(ms[w][row] - mx);
      L += wt*ls[w][row];
      A += wt*b2f(Os[w][row][col]);
    }
    const float val = A/L + b2f(qp[((size_t)bh*N_ + q0 + row)*HD_ + col]);
    attb[ftidx(grow0 + row, head*HD_ + col)] = f2b(val);
  }
}

// ---------------------------------------------------------------------------
// K5: output projection via MFMA, fragment-tiled A (attb) and B (Wpt).
// ---------------------------------------------------------------------------
__global__ __launch_bounds__(256) void k_proj(const bf_t* __restrict__ At,
    const bf_t* __restrict__ Wpt, const float* __restrict__ pb,
    float* __restrict__ out){
  const int wid = threadIdx.x >> 6, lane = threadIdx.x & 63;
  const int wr = wid & 1, wc = wid >> 1;
  const int nl = lane & 15, quad = lane >> 4;
  const int r0 = blockIdx.x*64 + wr*32;
  const int mt0 = r0 >> 4;
  const int nt0 = blockIdx.y*8 + wc*4;
  f32x4 acc[2][4];
  #pragma unroll
  for (int i = 0; i < 2; ++i)
    #pragma unroll
    for (int j = 0; j < 4; ++j) acc[i][j] = (f32x4){0.f,0.f,0.f,0.f};
  const bf_t* A0 = At  + ((size_t)mt0*12*64 + lane)*8;
  const bf_t* B0 = Wpt + ((size_t)nt0*12*64 + lane)*8;
  #pragma unroll 2
  for (int k0 = 0; k0 < 12; ++k0){
    const bf16x8 a0 = *(const bf16x8*)(A0 + k0*512);
    const bf16x8 a1 = *(const bf16x8*)(A0 + 12*512 + k0*512);
    bf16x8 bf[4];
    #pragma unroll
    for (int j = 0; j < 4; ++j) bf[j] = *(const bf16x8*)(B0 + (size_t)(j*12 + k0)*512);
    #pragma unroll
    for (int j = 0; j < 4; ++j){
      acc[0][j] = __builtin_amdgcn_mfma_f32_16x16x32_bf16(a0, bf[j], acc[0][j], 0, 0, 0);
      acc[1][j] = __builtin_amdgcn_mfma_f32_16x16x32_bf16(a1, bf[j], acc[1][j], 0, 0, 0);
    }
  }
  #pragma unroll
  for (int i = 0; i < 2; ++i){
    #pragma unroll
    for (int r = 0; r < 4; ++r){
      const int m = r0 + i*16 + quad*4 + r;
      #pragma unroll
      for (int j = 0; j < 4; ++j){
        const int col = (nt0 + j)*16 + nl;
        out[(size_t)m*DIM_ + col] = acc[i][j][r] + pb[col];
      }
    }
  }
}

// ---------------------------------------------------------------------------
extern "C" void kernel_launch(void* const* d_in, const int* in_sizes, int n_in,
                              void* d_out, int out_size, void* d_ws, size_t ws_size,
                              hipStream_t stream){
  const float* x      = (const float*)d_in[0];
  const float* qkv_w  = (const float*)d_in[1];
  const float* proj_w = (const float*)d_in[2];
  const float* proj_b = (const float*)d_in[3];
  const float* pqw    = (const float*)d_in[4];
  const float* pkw    = (const float*)d_in[5];
  const float* pvw    = (const float*)d_in[6];
  const float* nqw    = (const float*)d_in[7];
  const float* nqb    = (const float*)d_in[8];
  const float* nkw    = (const float*)d_in[9];
  const float* nkb    = (const float*)d_in[10];
  const float* nvw    = (const float*)d_in[11];
  const float* nvb    = (const float*)d_in[12];
  const float* rph    = (const float*)d_in[13];
  const float* rpw    = (const float*)d_in[14];
  const float* rpt    = (const float*)d_in[15];

  // Workspace (bytes), ~23.7 MB total. attb overlays raw_q after pooling.
  char* p = (char*)d_ws;
  const size_t RAW = (size_t)BH_*N_*HD_*2;       // 2,408,448 B
  const size_t AUG = (size_t)BH_*N_*CAUG_*2;     // 4,014,080 B
  bf_t* xb     = (bf_t*)(p);                     // frag-tiled
  bf_t* wqkvb  = (bf_t*)(p + RAW);               // frag-tiled
  bf_t* wprojb = (bf_t*)(p + RAW + 884736);      // frag-tiled
  char* p2 = p + RAW + 884736 + 294912;
  bf_t* raw_q  = (bf_t*)(p2);
  bf_t* raw_k  = (bf_t*)(p2 + RAW);
  bf_t* raw_v  = (bf_t*)(p2 + 2*RAW);
  bf_t* attb   = raw_q;                          // overlays raw_q (frag-tiled)
  bf_t* qp     = (bf_t*)(p2 + 3*RAW);
  bf_t* Qaug   = (bf_t*)(p2 + 4*RAW);
  bf_t* Kt     = (bf_t*)(p2 + 4*RAW + AUG);      // tiled Kaug
  bf_t* Vtt    = (bf_t*)(p2 + 4*RAW + 2*AUG);    // tiled V
  float* wtq   = (float*)(p2 + 4*RAW + 2*AUG + RAW);   // 3 x 27x96 fp32
  float* wtk   = wtq + 27*HD_;
  float* wtv   = wtk + 27*HD_;

  k_cast     <<<CAST_MBLOCKS + 31, 256, 0, stream>>>(x, xb, qkv_w, wqkvb, proj_w, wprojb,
                                                     pqw, pkw, pvw, wtq, wtk, wtv);
  k_qkv      <<<dim3(BN_/64, 9),  256, 0, stream>>>(xb, wqkvb, raw_q, raw_k, raw_v);
  k_pool_slab<<<3*784,            256, 0, stream>>>(raw_q, raw_k, raw_v,
                                                    wtq, wtk, wtv,
                                                    nqw, nqb, nkw, nkb, nvw, nvb,
                                                    rph, rpw, rpt,
                                                    qp, Qaug, Kt, Vtt);
  k_attn     <<<BH_*98,           512, 0, stream>>>(Qaug, Kt, Vtt, qp, attb);
  k_proj     <<<dim3(BN_/64, 3),  256, 0, stream>>>(attb, wprojb, proj_b, (float*)d_out);
}

// Round 13
// 189.043 us; speedup vs baseline: 1.0330x; 1.0043x over previous
//
#include <hip/hip_runtime.h>

// Problem constants (fixed by reference)
#define B_    2
#define NH_   4
#define T_    8
#define H_    14
#define W_    14
#define HW_   196             // H*W
#define HD_   96
#define DIM_  384
#define N_    1568            // T*H*W
#define BH_   (B_*NH_)        // 8
#define BN_   (B_*N_)         // 3136
#define BHN_  (BH_*N_)        // 12544
#define CAUG_ 160             // 96 + 36 one-hot/bias + 28 pad

typedef unsigned short bf_t;
typedef unsigned int   u32;
typedef __attribute__((ext_vector_type(8))) short bf16x8;
typedef __attribute__((ext_vector_type(4))) float f32x4;

#define LOG2E 1.4426950408889634f
#define QSCALE_LOG2E 0.14724445f   /* 96^-0.5 * log2(e) */

static __device__ __forceinline__ float lo16(u32 v){ union{u32 i; float f;}x; x.i = v<<16;           return x.f; }
static __device__ __forceinline__ float hi16(u32 v){ union{u32 i; float f;}x; x.i = v & 0xffff0000u; return x.f; }
static __device__ __forceinline__ float b2f(bf_t v){ union{u32 i; float f;}x; x.i = ((u32)v)<<16;    return x.f; }
static __device__ __forceinline__ bf_t  f2b(float f){
  union{float f; u32 i;} x; x.f = f;
  return (bf_t)((x.i + 0x7fffu + ((x.i>>16)&1u)) >> 16);   // RNE
}
static __device__ __forceinline__ u32 pack2(float a, float b){
  return (u32)f2b(a) | ((u32)f2b(b) << 16);
}
// fragment-tile index for a row-major [R][384] matrix element (row, k)
static __device__ __forceinline__ size_t ftidx(int row, int k){
  return ((((size_t)(row>>4))*12 + (k>>5))*64 + ((k>>3)&3)*16 + (row&15))*8 + (k&7);
}

// ---------------------------------------------------------------------------
// K0: cast x / qkv_w / proj_w fp32 -> bf16 in FRAGMENT-TILED layout, plus
// conv-weight transpose [96][27]->[27][96] fp32 (last 31 blocks).
// R24 (verified -2.8us): tile-per-wave; one wave owns one 16x32 fragment
// tile -> lane l writes 16B contiguous, wave writes a coalesced 1KB tile.
// ---------------------------------------------------------------------------
#define NA_ (BN_*DIM_)        // 1,204,224
#define NB_ (3*DIM_*DIM_)     //   442,368
#define NC_ (DIM_*DIM_)       //   147,456
#define TILES_X 2352          // (3136/16)*(384/32)
#define TILES_B 864           // (1152/16)*12
#define TILES_C 288           // (384/16)*12
#define CAST_MBLOCKS ((TILES_X+TILES_B+TILES_C)/4)   // 876 exactly

__global__ __launch_bounds__(256) void k_cast(
    const float* __restrict__ a, bf_t* __restrict__ ad,
    const float* __restrict__ b, bf_t* __restrict__ bd,
    const float* __restrict__ c, bf_t* __restrict__ cd,
    const float* __restrict__ wq, const float* __restrict__ wk,
    const float* __restrict__ wv, float* __restrict__ tq,
    float* __restrict__ tk, float* __restrict__ tv){
  if (blockIdx.x < CAST_MBLOCKS){
    const int tile = blockIdx.x*4 + (threadIdx.x >> 6);
    const int lane = threadIdx.x & 63;
    const float* src; bf_t* dst; int tl;
    if (tile < TILES_X)                { src = a; dst = ad; tl = tile; }
    else if (tile < TILES_X + TILES_B) { src = b; dst = bd; tl = tile - TILES_X; }
    else                               { src = c; dst = cd; tl = tile - TILES_X - TILES_B; }
    const int mt = tl / 12, kt = tl % 12;
    const int row = mt*16 + (lane & 15);
    const int k0  = kt*32 + (lane >> 4)*8;
    const float4 v0 = *(const float4*)(src + (size_t)row*DIM_ + k0);
    const float4 v1 = *(const float4*)(src + (size_t)row*DIM_ + k0 + 4);
    const u32 w0 = pack2(v0.x, v0.y), w1 = pack2(v0.z, v0.w);
    const u32 w2 = pack2(v1.x, v1.y), w3 = pack2(v1.z, v1.w);
    *(uint4*)(dst + (size_t)tl*512 + lane*8) = make_uint4(w0, w1, w2, w3);
  } else {
    const int idx = (blockIdx.x - CAST_MBLOCKS)*256 + threadIdx.x;
    if (idx >= 3*HD_*27) return;
    const int t = idx / (HD_*27), rem = idx % (HD_*27);
    const int ch = rem / 27, j = rem % 27;
    const float* s = (t==0)? wq : (t==1)? wk : wv;
    float* d       = (t==0)? tq : (t==1)? tk : tv;
    d[j*HD_ + ch] = s[ch*27 + j];
  }
}

// ---------------------------------------------------------------------------
// K1: QKV GEMM via MFMA, fragment-tiled operands.
// R23: scalar-store epilogue (LDS-staged variant measured +1.5us; scalar
// stores were already hidden under GEMM wave-level overlap).
// ---------------------------------------------------------------------------
__global__ __launch_bounds__(256) void k_qkv(const bf_t* __restrict__ Xt,
    const bf_t* __restrict__ Wt,
    bf_t* __restrict__ q, bf_t* __restrict__ k, bf_t* __restrict__ v){
  const int wid = threadIdx.x >> 6, lane = threadIdx.x & 63;
  const int wr = wid & 1, wc = wid >> 1;
  const int nl = lane & 15, quad = lane >> 4;
  const int r0 = blockIdx.x*64 + wr*32;
  const int mt0 = r0 >> 4;
  const int nt0 = blockIdx.y*8 + wc*4;
  f32x4 acc[2][4];
  #pragma unroll
  for (int i = 0; i < 2; ++i)
    #pragma unroll
    for (int j = 0; j < 4; ++j) acc[i][j] = (f32x4){0.f,0.f,0.f,0.f};
  const bf_t* A0 = Xt + ((size_t)mt0*12*64 + lane)*8;
  const bf_t* B0 = Wt + ((size_t)nt0*12*64 + lane)*8;
  #pragma unroll 2
  for (int k0 = 0; k0 < 12; ++k0){
    const bf16x8 a0 = *(const bf16x8*)(A0 + k0*512);
    const bf16x8 a1 = *(const bf16x8*)(A0 + 12*512 + k0*512);
    bf16x8 bf[4];
    #pragma unroll
    for (int j = 0; j < 4; ++j) bf[j] = *(const bf16x8*)(B0 + (size_t)(j*12 + k0)*512);
    #pragma unroll
    for (int j = 0; j < 4; ++j){
      acc[0][j] = __builtin_amdgcn_mfma_f32_16x16x32_bf16(a0, bf[j], acc[0][j], 0, 0, 0);
      acc[1][j] = __builtin_amdgcn_mfma_f32_16x16x32_bf16(a1, bf[j], acc[1][j], 0, 0, 0);
    }
  }
  #pragma unroll
  for (int i = 0; i < 2; ++i){
    #pragma unroll
    for (int r = 0; r < 4; ++r){
      const int m  = r0 + i*16 + quad*4 + r;
      const int bb = m / N_, nn = m % N_;
      #pragma unroll
      for (int j = 0; j < 4; ++j){
        const int col = (nt0 + j)*16 + nl;
        const int s = col / DIM_, rem = col - s*DIM_;
        const int head = rem / HD_, hc = rem % HD_;
        bf_t* dst = (s==0) ? q : (s==1) ? k : v;
        dst[((size_t)(bb*NH_ + head)*N_ + nn)*HD_ + hc] = f2b(acc[i][j][r]);
      }
    }
  }
}

static __device__ __forceinline__ void ln_butterfly(
    float v0, float v1, float& mean, float& rstd){
  float s  = v0 + v1;
  float s2 = v0*v0 + v1*v1;
  #pragma unroll
  for (int off = 32; off > 0; off >>= 1){
    s  += __shfl_xor(s,  off);
    s2 += __shfl_xor(s2, off);
  }
  mean = s * (1.f/HD_);
  const float var = fmaxf(s2*(1.f/HD_) - mean*mean, 0.f);
  rstd = rsqrtf(var + 1e-6f);
}

// ---------------------------------------------------------------------------
// K2: LDS-slab pooled conv+LN, 16 tokens/block (4 waves x 4 tokens).
// Halo slab 162 rows (3t x 3h x 18w) x 96ch bf16 = 31.1 KB.
// R16 form (best measured). Ledger: R14 forced-occupancy spill (-),
// R17 deep pipeline (-), R19 XCD pinning (FETCH 22->3.9MB, timing-neutral).
// ---------------------------------------------------------------------------
union PoolSM {
  bf_t  slab[162][HD_];       // 31,104 B  (phase 1)
  float qtmp[4][4][HD_];      //  6,144 B  (phase 2, sec 0; per-wave)
  u32   vres[16][48];         //  3,072 B  (phase 2, sec 2)
};

__global__ __launch_bounds__(256) void k_pool_slab(
    const bf_t* __restrict__ qr_, const bf_t* __restrict__ kr_, const bf_t* __restrict__ vr_,
    const float* __restrict__ wtq, const float* __restrict__ wtk, const float* __restrict__ wtv,
    const float* __restrict__ gq, const float* __restrict__ bq,
    const float* __restrict__ gk, const float* __restrict__ bk,
    const float* __restrict__ gv, const float* __restrict__ bv,
    const float* __restrict__ rph, const float* __restrict__ rpw,
    const float* __restrict__ rpt,
    bf_t* __restrict__ qp, bf_t* __restrict__ Qaug,
    bf_t* __restrict__ Kt, bf_t* __restrict__ Vtt){
  __shared__ __align__(16) PoolSM sm;
  const int wid = threadIdx.x >> 6, lane = threadIdx.x & 63;
  const int sec = blockIdx.x / 784;
  const int rr_ = blockIdx.x % 784;
  const int bh = rr_ / 98, tok0 = (rr_ % 98)*16;
  const bf_t*  src = (sec==0)? qr_ : (sec==1)? kr_ : vr_;
  const float* wt  = (sec==0)? wtq : (sec==1)? wtk : wtv;
  const float* g   = (sec==0)? gq  : (sec==1)? gk  : gv;
  const float* be  = (sec==0)? bq  : (sec==1)? bk  : bv;
  const bf_t* base = src + (size_t)bh*N_*HD_;

  // per-lane channel pair; first weight trio + LN params overlap staging
  const int c0 = (lane < 48) ? 2*lane : 0;
  float2 wcur[3], wnxt[3];
  #pragma unroll
  for (int dw = 0; dw < 3; ++dw) wcur[dw] = *(const float2*)(wt + dw*HD_ + c0);
  const float gg0 = g[c0], gg1 = g[c0+1], be0 = be[c0], be1 = be[c0+1];

  // ---- staging: batched loads into regs, then LDS writes (vmcnt pipeline) --
  {
    uint4 stg[8];
    #pragma unroll
    for (int it = 0; it < 8; ++it){
      const int li = threadIdx.x + it*256;
      const int lc = (li < 162*12) ? li : (162*12 - 1);
      const int rw = lc / 12, ss = lc % 12;
      const int aa = rw/54, bb2 = (rw%54)/18, cc = rw%18;
      int nn = tok0 + (aa-1)*HW_ + (bb2-1)*W_ + (cc-1);
      nn = min(max(nn, 0), N_-1);
      stg[it] = *(const uint4*)(base + (size_t)nn*HD_ + ss*8);
    }
    #pragma unroll
    for (int it = 0; it < 8; ++it){
      const int li = threadIdx.x + it*256;
      if (li < 162*12){
        const int rw = li / 12, ss = li % 12;
        *(uint4*)&sm.slab[rw][ss*8] = stg[it];
      }
    }
  }
  __syncthreads();

  // token coordinates (wave-uniform) + 27-bit validity masks
  int tt[4], hh[4], ww[4];
  u32 mr[4];
  #pragma unroll
  for (int tk = 0; tk < 4; ++tk){
    const int n = tok0 + wid*4 + tk;
    tt[tk] = n / HW_;
    const int rm = n % HW_;
    hh[tk] = rm / W_; ww[tk] = rm % W_;
    const u32 wb = (ww[tk] > 0 ? 1u : 0u) | 2u | (ww[tk] < W_-1 ? 4u : 0u);
    const u32 h9 = (hh[tk] > 0 ? wb : 0u) | (wb << 3) | (hh[tk] < H_-1 ? (wb << 6) : 0u);
    mr[tk] = (tt[tk] > 0 ? h9 : 0u) | (h9 << 9) | (tt[tk] < T_-1 ? (h9 << 18) : 0u);
  }

  // ---- phase 1: conv, software-pipelined row reads ----
  float v0[4] = {0.f,0.f,0.f,0.f}, v1[4] = {0.f,0.f,0.f,0.f};
  u32 rr[6], rrn[6];
  #pragma unroll
  for (int s = 0; s < 6; ++s) rr[s] = *(const u32*)&sm.slab[wid*4 + s][c0];
  #pragma unroll 1
  for (int j9 = 0; j9 < 9; ++j9){
    if (j9 < 8){
      const int jn = j9 + 1;
      const int rbn = (jn/3)*54 + (jn%3)*18 + wid*4;
      #pragma unroll
      for (int s = 0; s < 6; ++s) rrn[s] = *(const u32*)&sm.slab[rbn + s][c0];
      #pragma unroll
      for (int dw = 0; dw < 3; ++dw)
        wnxt[dw] = *(const float2*)(wt + (jn*3 + dw)*HD_ + c0);
    }
    #pragma unroll
    for (int tk = 0; tk < 4; ++tk){
      #pragma unroll
      for (int dw = 0; dw < 3; ++dw){
        const u32 d = (mr[tk] & (1u << dw)) ? rr[tk+dw] : 0u;
        v0[tk] = fmaf(wcur[dw].x, lo16(d), v0[tk]);
        v1[tk] = fmaf(wcur[dw].y, hi16(d), v1[tk]);
      }
      mr[tk] >>= 3;
    }
    #pragma unroll
    for (int s = 0; s < 6; ++s) rr[s] = rrn[s];
    #pragma unroll
    for (int dw = 0; dw < 3; ++dw) wcur[dw] = wnxt[dw];
  }
  // LayerNorm per token (results stay in v0/v1)
  #pragma unroll
  for (int tk = 0; tk < 4; ++tk){
    float a = v0[tk], b = v1[tk];
    if (lane >= 48){ a = 0.f; b = 0.f; }
    float mean, rstd;
    ln_butterfly(a, b, mean, rstd);
    v0[tk] = (a - mean)*rstd*gg0 + be0;
    v1[tk] = (b - mean)*rstd*gg1 + be1;
  }

  // ---- phase 2: outputs (qtmp/vres overlay slab; barrier before overlay) --
  if (sec == 0){
    __syncthreads();                              // slab -> qtmp overlay
    #pragma unroll
    for (int tk = 0; tk < 4; ++tk){
      const int n = tok0 + wid*4 + tk;
      const int token = bh*N_ + n;
      if (lane < 48){
        ((u32*)qp)  [(size_t)token*48 + lane] = pack2(v0[tk], v1[tk]);
        ((u32*)Qaug)[(size_t)token*80 + lane] = pack2(v0[tk]*QSCALE_LOG2E, v1[tk]*QSCALE_LOG2E);
        *(float2*)&sm.qtmp[wid][tk][c0] = make_float2(v0[tk], v1[tk]);
      }
    }
    // qtmp written/read by the SAME wave -> ordered by lgkmcnt, no barrier
    #pragma unroll
    for (int tk = 0; tk < 4; ++tk){
      const int n = tok0 + wid*4 + tk;
      const int token = bh*N_ + n;
      if (lane < 36){
        const float* tb; int idx;
        if (lane < 14)      { tb = rph; idx = hh[tk] - lane      + 13; }
        else if (lane < 28) { tb = rpw; idx = ww[tk] - (lane-14) + 13; }
        else                { tb = rpt; idx = tt[tk] - (lane-28) +  7; }
        const float4* t4 = (const float4*)(tb + (size_t)idx*HD_);
        const float4* q4 = (const float4*)&sm.qtmp[wid][tk][0];
        float ap[4] = {0.f, 0.f, 0.f, 0.f};
        #pragma unroll
        for (int i = 0; i < 24; ++i){
          const float4 rv = t4[i];
          const float4 qv = q4[i];                 // ds_read_b128 broadcast
          ap[i & 3] = fmaf(qv.x, rv.x,
                      fmaf(qv.y, rv.y,
                      fmaf(qv.z, rv.z,
                      fmaf(qv.w, rv.w, ap[i & 3]))));
        }
        const float acc = (ap[0] + ap[1]) + (ap[2] + ap[3]);
        Qaug[(size_t)token*CAUG_ + HD_ + lane] = f2b(acc * LOG2E);
      } else {
        Qaug[(size_t)token*CAUG_ + HD_ + lane] = 0;
      }
    }
  } else if (sec == 1){
    // no LDS use in this branch -> no barrier needed
    #pragma unroll
    for (int tk = 0; tk < 4; ++tk){
      const int n = tok0 + wid*4 + tk;
      const int tl = n >> 4, nr = n & 15;
      if (lane < 48){
        const size_t idx = ((((size_t)bh*98 + tl)*5 + (lane>>4))*64
                           + ((lane&15)>>2)*16 + nr)*4 + (lane&3);
        ((u32*)Kt)[idx] = pack2(v0[tk], v1[tk]);
      } else {
        const int m = lane - 48;
        u32 pr_[2];
        #pragma unroll
        for (int h2 = 0; h2 < 2; ++h2){
          u32 w_ = 0;
          #pragma unroll
          for (int e = 0; e < 2; ++e){
            const int jj = 4*m + 2*h2 + e;
            bool on = (jj < 14) ? (jj == hh[tk]) : (jj < 28) ? (jj-14 == ww[tk])
                     : (jj < 36) ? (jj-28 == tt[tk]) : false;
            if (on) w_ |= (0x3F80u << (16*e));
          }
          pr_[h2] = w_;
        }
        const size_t bidx = ((((size_t)bh*98 + tl)*5 + (3 + (m>>3)))*64
                            + ((m&7)>>1)*16 + nr)*4 + 2*(m&1);
        *(uint2*)((u32*)Kt + bidx) = make_uint2(pr_[0], pr_[1]);
      }
    }
  } else {
    __syncthreads();                              // slab -> vres overlay
    #pragma unroll
    for (int tk = 0; tk < 4; ++tk){
      if (lane < 48) sm.vres[wid*4 + tk][lane] = pack2(v0[tk], v1[tk]);
    }
    __syncthreads();
    if (threadIdx.x < 2*HD_){
      const int grp = threadIdx.x / HD_, c = threadIdx.x % HD_;
      const int t0g = grp*8;
      u32 o[4];
      #pragma unroll
      for (int i = 0; i < 4; ++i){
        const u32 a = sm.vres[t0g + 2*i][c>>1], b = sm.vres[t0g + 2*i+1][c>>1];
        const u32 ra = (c&1) ? (a >> 16) : (a & 0xffffu);
        const u32 rb = (c&1) ? (b >> 16) : (b & 0xffffu);
        o[i] = ra | (rb << 16);
      }
      const int n0g = tok0 + t0g;
      const int pr = n0g >> 5, qd = (n0g & 31) >> 3;
      bf_t* dst = Vtt + ((((size_t)bh*49 + pr)*6 + (c>>4))*64 + qd*16 + (c&15))*8;
      *(uint4*)dst = make_uint4(o[0], o[1], o[2], o[3]);
    }
  }
}

// ---------------------------------------------------------------------------
// K4: MFMA flash attention, 8-wave in-block split-K, fragment-tiled K/V.
// R25: restructured combine epilogue. Old: per-ELEMENT recompute of the
// 8-way merge weights (8 fmax + 8 exp2 x 1536) + 1536 scalar 2B ftidx
// stores (16B per 256B chunk, ~4x write amplification -- same pathology
// R24 fixed in k_cast). New: phase A computes wts[row][w] =
// exp2(ms-mx)/(sum exp2*ls) ONCE per row (16 lanes); phase B (384 thr x
// 4 cols) does val = sum wts*Os + qp with ushort4 Os/qp reads and ONE
// uint2 (8B contiguous-in-ftidx) store per thread.
// ---------------------------------------------------------------------------
__global__ __launch_bounds__(512) void k_attn(
    const bf_t* __restrict__ Qaug, const bf_t* __restrict__ Kt,
    const bf_t* __restrict__ Vtt, const bf_t* __restrict__ qp,
    bf_t* __restrict__ attb){
  __shared__ __align__(16) short Pb[8][16][40];   // per-wave P tile (+8 pad)
  __shared__ bf_t Os[8][16][96];                  // per-wave partial O (bf16)
  __shared__ float ms[8][16], ls[8][16];          // per-wave partial m, l
  __shared__ float wts[16][8];                    // merged per-row weights
  const int wid = threadIdx.x >> 6, lane = threadIdx.x & 63;
  const int bh = blockIdx.x / 98, qt = blockIdx.x % 98;
  const int q0 = qt*16;
  const int nl = lane & 15, quad = lane >> 4;

  bf16x8 qa[5];
  {
    const bf_t* Qrow = Qaug + ((size_t)bh*N_ + q0 + nl)*CAUG_ + quad*8;
    #pragma unroll
    for (int i = 0; i < 5; ++i) qa[i] = *(const bf16x8*)(Qrow + i*32);
  }
  short* Pw = &Pb[wid][0][0];

  f32x4 O[6];
  #pragma unroll
  for (int i = 0; i < 6; ++i) O[i] = (f32x4){0.f,0.f,0.f,0.f};
  float mc[4]   = {0.f,0.f,0.f,0.f};
  float rmax[4] = {-3e38f,-3e38f,-3e38f,-3e38f};
  float l[4]    = {0.f,0.f,0.f,0.f};

  auto s_tile = [&](int tl, int half){
    const bf_t* Kp = Kt + (((size_t)bh*98 + tl)*5*64 + lane)*8;
    f32x4 s = (f32x4){0.f,0.f,0.f,0.f};
    #pragma unroll
    for (int i = 0; i < 5; ++i)
      s = __builtin_amdgcn_mfma_f32_16x16x32_bf16(qa[i], *(const bf16x8*)(Kp + i*512), s, 0, 0, 0);
    #pragma unroll
    for (int r = 0; r < 4; ++r){
      rmax[r] = fmaxf(rmax[r], s[r]);
      const float p = exp2f(s[r] - mc[r]);
      l[r] += p;
      Pw[(quad*4 + r)*40 + half*16 + nl] = (short)f2b(p);
    }
  };
  auto rescale = [&](){
    #pragma unroll
    for (int r = 0; r < 4; ++r){
      float tm = rmax[r];
      tm = fmaxf(tm, __shfl_xor(tm, 1));
      tm = fmaxf(tm, __shfl_xor(tm, 2));
      tm = fmaxf(tm, __shfl_xor(tm, 4));
      tm = fmaxf(tm, __shfl_xor(tm, 8));
      const float mn = fmaxf(mc[r], tm);
      const float al = exp2f(mc[r] - mn);
      mc[r] = mn; l[r] *= al;
      #pragma unroll
      for (int ct = 0; ct < 6; ++ct) O[ct][r] *= al;
    }
  };

  const int p0 = (wid == 0) ? 0 : (7 + 6*(wid-1));
  const int npairs = (wid == 0) ? 7 : 6;
  #pragma unroll 1
  for (int pi = 0; pi < npairs; ++pi){
    const int kp = p0 + pi;
    s_tile(2*kp,     0);
    s_tile(2*kp + 1, 1);
    const bf16x8 pa = *(const bf16x8*)(Pw + nl*40 + quad*8);
    const bf_t* Vp = Vtt + (((size_t)bh*49 + kp)*6*64 + lane)*8;
    #pragma unroll
    for (int ct = 0; ct < 6; ++ct)
      O[ct] = __builtin_amdgcn_mfma_f32_16x16x32_bf16(pa, *(const bf16x8*)(Vp + ct*512), O[ct], 0, 0, 0);
    if (pi == npairs-1) rescale();
  }

  #pragma unroll
  for (int r = 0; r < 4; ++r){
    float ls_ = l[r];
    ls_ += __shfl_xor(ls_, 1); ls_ += __shfl_xor(ls_, 2);
    ls_ += __shfl_xor(ls_, 4); ls_ += __shfl_xor(ls_, 8);
    if (nl == 0){ ms[wid][quad*4 + r] = mc[r]; ls[wid][quad*4 + r] = ls_; }
    #pragma unroll
    for (int ct = 0; ct < 6; ++ct) Os[wid][quad*4 + r][ct*16 + nl] = f2b(O[ct][r]);
  }
  __syncthreads();

  // ---- phase A: per-row merge weights (once, folded with 1/L) ----
  if (threadIdx.x < 16){
    const int row = threadIdx.x;
    float mx = -3e38f;
    #pragma unroll
    for (int w = 0; w < 8; ++w) mx = fmaxf(mx, ms[w][row]);
    float wv[8]; float L = 0.f;
    #pragma unroll
    for (int w = 0; w < 8; ++w){
      wv[w] = exp2f(ms[w][row] - mx);
      L = fmaf(wv[w], ls[w][row], L);
    }
    const float rL = 1.f / L;
    #pragma unroll
    for (int w = 0; w < 8; ++w) wts[row][w] = wv[w]*rL;
  }
  __syncthreads();

  // ---- phase B: 384 threads x 4 cols, vectorized reads + uint2 store ----
  if (threadIdx.x < 384){
    const int row = threadIdx.x / 24, gg = threadIdx.x % 24;
    const int col0 = gg*4;
    float w8[8];
    #pragma unroll
    for (int w = 0; w < 8; ++w) w8[w] = wts[row][w];
    float a0 = 0.f, a1 = 0.f, a2 = 0.f, a3 = 0.f;
    #pragma unroll
    for (int w = 0; w < 8; ++w){
      const ushort4 o4 = *(const ushort4*)&Os[w][row][col0];
      a0 = fmaf(w8[w], b2f(o4.x), a0);
      a1 = fmaf(w8[w], b2f(o4.y), a1);
      a2 = fmaf(w8[w], b2f(o4.z), a2);
      a3 = fmaf(w8[w], b2f(o4.w), a3);
    }
    const ushort4 qv = *(const ushort4*)(qp + ((size_t)bh*N_ + q0 + row)*HD_ + col0);
    const u32 lo = pack2(a0 + b2f(qv.x), a1 + b2f(qv.y));
    const u32 hi = pack2(a2 + b2f(qv.z), a3 + b2f(qv.w));
    const int bb = bh >> 2, head = bh & 3;
    const int grow0 = bb*N_ + q0;                 // multiple of 16
    *(uint2*)(attb + ftidx(grow0 + row, head*HD_ + col0)) = make_uint2(lo, hi);
  }
}

// ---------------------------------------------------------------------------
// K5: output projection via MFMA, fragment-tiled A (attb) and B (Wpt).
// ---------------------------------------------------------------------------
__global__ __launch_bounds__(256) void k_proj(const bf_t* __restrict__ At,
    const bf_t* __restrict__ Wpt, const float* __restrict__ pb,
    float* __restrict__ out){
  const int wid = threadIdx.x >> 6, lane = threadIdx.x & 63;
  const int wr = wid & 1, wc = wid >> 1;
  const int nl = lane & 15, quad = lane >> 4;
  const int r0 = blockIdx.x*64 + wr*32;
  const int mt0 = r0 >> 4;
  const int nt0 = blockIdx.y*8 + wc*4;
  f32x4 acc[2][4];
  #pragma unroll
  for (int i = 0; i < 2; ++i)
    #pragma unroll
    for (int j = 0; j < 4; ++j) acc[i][j] = (f32x4){0.f,0.f,0.f,0.f};
  const bf_t* A0 = At  + ((size_t)mt0*12*64 + lane)*8;
  const bf_t* B0 = Wpt + ((size_t)nt0*12*64 + lane)*8;
  #pragma unroll 2
  for (int k0 = 0; k0 < 12; ++k0){
    const bf16x8 a0 = *(const bf16x8*)(A0 + k0*512);
    const bf16x8 a1 = *(const bf16x8*)(A0 + 12*512 + k0*512);
    bf16x8 bf[4];
    #pragma unroll
    for (int j = 0; j < 4; ++j) bf[j] = *(const bf16x8*)(B0 + (size_t)(j*12 + k0)*512);
    #pragma unroll
    for (int j = 0; j < 4; ++j){
      acc[0][j] = __builtin_amdgcn_mfma_f32_16x16x32_bf16(a0, bf[j], acc[0][j], 0, 0, 0);
      acc[1][j] = __builtin_amdgcn_mfma_f32_16x16x32_bf16(a1, bf[j], acc[1][j], 0, 0, 0);
    }
  }
  #pragma unroll
  for (int i = 0; i < 2; ++i){
    #pragma unroll
    for (int r = 0; r < 4; ++r){
      const int m = r0 + i*16 + quad*4 + r;
      #pragma unroll
      for (int j = 0; j < 4; ++j){
        const int col = (nt0 + j)*16 + nl;
        out[(size_t)m*DIM_ + col] = acc[i][j][r] + pb[col];
      }
    }
  }
}

// ---------------------------------------------------------------------------
extern "C" void kernel_launch(void* const* d_in, const int* in_sizes, int n_in,
                              void* d_out, int out_size, void* d_ws, size_t ws_size,
                              hipStream_t stream){
  const float* x      = (const float*)d_in[0];
  const float* qkv_w  = (const float*)d_in[1];
  const float* proj_w = (const float*)d_in[2];
  const float* proj_b = (const float*)d_in[3];
  const float* pqw    = (const float*)d_in[4];
  const float* pkw    = (const float*)d_in[5];
  const float* pvw    = (const float*)d_in[6];
  const float* nqw    = (const float*)d_in[7];
  const float* nqb    = (const float*)d_in[8];
  const float* nkw    = (const float*)d_in[9];
  const float* nkb    = (const float*)d_in[10];
  const float* nvw    = (const float*)d_in[11];
  const float* nvb    = (const float*)d_in[12];
  const float* rph    = (const float*)d_in[13];
  const float* rpw    = (const float*)d_in[14];
  const float* rpt    = (const float*)d_in[15];

  // Workspace (bytes), ~23.7 MB total. attb overlays raw_q after pooling.
  char* p = (char*)d_ws;
  const size_t RAW = (size_t)BH_*N_*HD_*2;       // 2,408,448 B
  const size_t AUG = (size_t)BH_*N_*CAUG_*2;     // 4,014,080 B
  bf_t* xb     = (bf_t*)(p);                     // frag-tiled
  bf_t* wqkvb  = (bf_t*)(p + RAW);               // frag-tiled
  bf_t* wprojb = (bf_t*)(p + RAW + 884736);      // frag-tiled
  char* p2 = p + RAW + 884736 + 294912;
  bf_t* raw_q  = (bf_t*)(p2);
  bf_t* raw_k  = (bf_t*)(p2 + RAW);
  bf_t* raw_v  = (bf_t*)(p2 + 2*RAW);
  bf_t* attb   = raw_q;                          // overlays raw_q (frag-tiled)
  bf_t* qp     = (bf_t*)(p2 + 3*RAW);
  bf_t* Qaug   = (bf_t*)(p2 + 4*RAW);
  bf_t* Kt     = (bf_t*)(p2 + 4*RAW + AUG);      // tiled Kaug
  bf_t* Vtt    = (bf_t*)(p2 + 4*RAW + 2*AUG);    // tiled V
  float* wtq   = (float*)(p2 + 4*RAW + 2*AUG + RAW);   // 3 x 27x96 fp32
  float* wtk   = wtq + 27*HD_;
  float* wtv   = wtk + 27*HD_;

  k_cast     <<<CAST_MBLOCKS + 31, 256, 0, stream>>>(x, xb, qkv_w, wqkvb, proj_w, wprojb,
                                                     pqw, pkw, pvw, wtq, wtk, wtv);
  k_qkv      <<<dim3(BN_/64, 9),  256, 0, stream>>>(xb, wqkvb, raw_q, raw_k, raw_v);
  k_pool_slab<<<3*784,            256, 0, stream>>>(raw_q, raw_k, raw_v,
                                                    wtq, wtk, wtv,
                                                    nqw, nqb, nkw, nkb, nvw, nvb,
                                                    rph, rpw, rpt,
                                                    qp, Qaug, Kt, Vtt);
  k_attn     <<<BH_*98,           512, 0, stream>>>(Qaug, Kt, Vtt, qp, attb);
  k_proj     <<<dim3(BN_/64, 3),  256, 0, stream>>>(attb, wprojb, proj_b, (float*)d_out);
}